// Round 1
// baseline (330.479 us; speedup 1.0000x reference)
//
#include <hip/hip_runtime.h>

typedef unsigned short u16;
typedef float  f32x4  __attribute__((ext_vector_type(4)));
typedef __bf16 bf16x8 __attribute__((ext_vector_type(8)));
typedef u16    u16x4  __attribute__((ext_vector_type(4)));

#define DEV __device__ __forceinline__

DEV u16 f2bf(float f) {                 // round-to-nearest-even f32 -> bf16 bits
  union { float f; unsigned u; } x; x.f = f;
  unsigned r = x.u + 0x7fffu + ((x.u >> 16) & 1u);
  return (u16)(r >> 16);
}

DEV f32x4 mfma16(bf16x8 a, bf16x8 b, f32x4 c) {
  return __builtin_amdgcn_mfma_f32_16x16x32_bf16(a, b, c, 0, 0, 0);
}

DEV void gload16(const void* g, void* l) {   // async global->LDS, 16B/lane
  __builtin_amdgcn_global_load_lds(
      (__attribute__((address_space(1))) void*)g,
      (__attribute__((address_space(3))) void*)l, 16, 0, 0);
}

// ---------------------------------------------------------------- layernorm
// One block (256 thr) per row. C in {768,1024}; C/4 <= 256. out bf16, folded scale.
__global__ void ln_rows(const float* __restrict__ x, const float* __restrict__ g,
                        const float* __restrict__ bta, u16* __restrict__ y,
                        int C, float outscale)
{
  const int row = blockIdx.x;
  const int tid = threadIdx.x;
  const int n4 = C >> 2;
  const float* xr = x + (size_t)row * C;
  f32x4 v = {0.f, 0.f, 0.f, 0.f};
  if (tid < n4) v = *(const f32x4*)(xr + 4 * tid);
  float s1 = v[0] + v[1] + v[2] + v[3];
  float s2 = v[0]*v[0] + v[1]*v[1] + v[2]*v[2] + v[3]*v[3];
#pragma unroll
  for (int o = 32; o > 0; o >>= 1) {
    s1 += __shfl_xor(s1, o, 64);
    s2 += __shfl_xor(s2, o, 64);
  }
  __shared__ float red[8];
  const int lane = tid & 63, wv = tid >> 6;
  if (lane == 0) { red[wv] = s1; red[4 + wv] = s2; }
  __syncthreads();
  s1 = red[0] + red[1] + red[2] + red[3];
  s2 = red[4] + red[5] + red[6] + red[7];
  const float mu = s1 / C;
  const float rs = rsqrtf(s2 / C - mu * mu + 1e-5f);
  if (tid < n4) {
    f32x4 gg = *(const f32x4*)(g + 4 * tid);
    f32x4 bb = *(const f32x4*)(bta + 4 * tid);
    u16x4 o4;
#pragma unroll
    for (int j = 0; j < 4; ++j)
      o4[j] = f2bf(((v[j] - mu) * rs * gg[j] + bb[j]) * outscale);
    *(u16x4*)(y + (size_t)row * C + 4 * tid) = o4;
  }
}

// ------------------------------------------------------- weight fp32 -> bf16^T
// w[K][N] f32 -> wt[N][K] bf16. K,N multiples of 32. 256 threads.
__global__ void transpose_w(const float* __restrict__ w, u16* __restrict__ wt,
                            int K, int N)
{
  __shared__ float t[32][33];
  const int k0 = blockIdx.x * 32, n0 = blockIdx.y * 32;
  const int tx = threadIdx.x & 31, ty = threadIdx.x >> 5;
#pragma unroll
  for (int i = ty; i < 32; i += 8)
    t[i][tx] = w[(size_t)(k0 + i) * N + n0 + tx];
  __syncthreads();
#pragma unroll
  for (int i = ty; i < 32; i += 8)
    wt[(size_t)(n0 + i) * K + k0 + tx] = f2bf(t[tx][i]);
}

// ------------------------------------------------------------- V transpose
// v[b*1024+j][768] bf16 -> vt[(bh*64+d)*1024+j] bf16
__global__ void transpose_v(const u16* __restrict__ v, u16* __restrict__ vt)
{
  __shared__ u16 t[64][65];
  const int bh = blockIdx.x, b = bh / 12, h = bh - b * 12;
  const int j0 = blockIdx.y * 64;
  const int tx = threadIdx.x & 63, ty = threadIdx.x >> 6;
#pragma unroll
  for (int i = ty; i < 64; i += 4)
    t[i][tx] = v[(size_t)(b * 1024 + j0 + i) * 768 + h * 64 + tx];
  __syncthreads();
#pragma unroll
  for (int i = ty; i < 64; i += 4)
    vt[((size_t)bh * 64 + i) * 1024 + j0 + tx] = t[tx][i];
}

// ------------------------------------------------------------------- GEMM
// C[M][N] = A[M][K] * Bt[N][K]^T   (A,Bt bf16 row-major; fp32 accum)
// MODE 0: fp32 store; MODE 1: bf16 store; MODE 2: fp32 + bias store.
// 128x128 tile, BK=32, 4 waves (2x2), each wave 64x64 via 4x4 16x16x32 MFMA.
template<int MODE>
__global__ __launch_bounds__(256)
void gemm_bt(const u16* __restrict__ A, const u16* __restrict__ Bt,
             void* __restrict__ Cp, const float* __restrict__ bias,
             int M, int N, int K)
{
  __shared__ __align__(16) u16 As[128 * 32];
  __shared__ __align__(16) u16 Bs[128 * 32];
  const int tid  = threadIdx.x;
  const int lane = tid & 63;
  const int wave = tid >> 6;
  const int bm = blockIdx.x * 128;
  const int bn = blockIdx.y * 128;
  const int wm = (wave >> 1) * 64;
  const int wn = (wave & 1) * 64;
  const int fr = lane & 15;
  const int fk = (lane >> 4) * 8;

  f32x4 acc[4][4] = {};

  const char* gA0 = (const char*)(A  + (size_t)bm * K);
  const char* gB0 = (const char*)(Bt + (size_t)bn * K);
  const int off0 = tid * 16;                 // byte offset in 8KB tile
  const size_t rowpitch = (size_t)K * 2;

  for (int k0 = 0; k0 < K; k0 += 32) {
#pragma unroll
    for (int c = 0; c < 2; ++c) {
      const int off  = off0 + c * 4096;
      const int row  = off >> 6;             // 64B per tile row (32 bf16)
      const int colb = off & 63;
      gload16(gA0 + (size_t)row * rowpitch + 2 * k0 + colb,
              (char*)As + wave * 1024 + c * 4096);
      gload16(gB0 + (size_t)row * rowpitch + 2 * k0 + colb,
              (char*)Bs + wave * 1024 + c * 4096);
    }
    __syncthreads();
    bf16x8 af[4], bg[4];
#pragma unroll
    for (int m = 0; m < 4; ++m)
      af[m] = *(const bf16x8*)&As[(wm + m * 16 + fr) * 32 + fk];
#pragma unroll
    for (int n = 0; n < 4; ++n)
      bg[n] = *(const bf16x8*)&Bs[(wn + n * 16 + fr) * 32 + fk];
#pragma unroll
    for (int m = 0; m < 4; ++m)
#pragma unroll
      for (int n = 0; n < 4; ++n)
        acc[m][n] = mfma16(af[m], bg[n], acc[m][n]);
    __syncthreads();
  }

  const int orow0 = bm + wm + 4 * (lane >> 4);
  const int ocol0 = bn + wn + fr;
#pragma unroll
  for (int m = 0; m < 4; ++m)
#pragma unroll
    for (int n = 0; n < 4; ++n)
#pragma unroll
      for (int r = 0; r < 4; ++r) {
        const int row = orow0 + m * 16 + r;
        const int col = ocol0 + n * 16;
        float v = acc[m][n][r];
        if (MODE == 2) v += bias[col];
        if (MODE == 1) ((u16*)Cp)[(size_t)row * N + col] = f2bf(v);
        else           ((float*)Cp)[(size_t)row * N + col] = v;
      }
}

// --------------------------------------------------------------- attention
// q[8192][768] bf16 (pre-scaled by 1/8 incl. bias), k[4096][768] bf16,
// vT[(bh*64+d)][1024] bf16, att[8192][768] bf16.
// grid(48, 32): block = (b,h) x q-block(64 rows); 4 waves x 16 q-rows.
__global__ __launch_bounds__(256)
void attn(const u16* __restrict__ q, const u16* __restrict__ k,
          const u16* __restrict__ vT, u16* __restrict__ att)
{
  const int bh = blockIdx.x;
  const int b = bh / 12, h = bh - b * 12;
  const int tid = threadIdx.x, lane = tid & 63, wave = tid >> 6;
  const int qrow0 = blockIdx.y * 64 + wave * 16;
  const int fr = lane & 15;
  const int fk = (lane >> 4) * 8;
  const int rg = lane >> 4;

  __shared__ __align__(16) u16 P[4][16][72];   // per-wave P tile, pad 72 (conflict-free b128)

  const u16* qp = q + (size_t)(b * 2048 + qrow0 + fr) * 768 + h * 64;
  const bf16x8 qf0 = *(const bf16x8*)(qp + fk);
  const bf16x8 qf1 = *(const bf16x8*)(qp + 32 + fk);

  f32x4 o[4] = {};                        // o[db]: d = db*16 + fr, rows rg*4+r
  float mrow[4] = {-1e30f, -1e30f, -1e30f, -1e30f};
  float lrow[4] = {};

  const u16* kbhd = k + (size_t)(b * 1024 + fr) * 768 + h * 64;
  const u16* vbh  = vT + (size_t)bh * 64 * 1024;

  for (int j0 = 0; j0 < 1024; j0 += 64) {
    // S = Q * K^T for 16q x 64j
    f32x4 s[4];
#pragma unroll
    for (int jt = 0; jt < 4; ++jt) {
      const u16* kp = kbhd + (size_t)(j0 + jt * 16) * 768;
      f32x4 t = {};
      t = mfma16(qf0, *(const bf16x8*)(kp + fk), t);
      t = mfma16(qf1, *(const bf16x8*)(kp + 32 + fk), t);
      s[jt] = t;
    }
    // online softmax stats (rows rg*4+r, reduce over 16 lanes = 64 cols)
    float mnew[4], sc[4], tsum[4];
#pragma unroll
    for (int r = 0; r < 4; ++r) {
      float tm = fmaxf(fmaxf(s[0][r], s[1][r]), fmaxf(s[2][r], s[3][r]));
#pragma unroll
      for (int m = 1; m < 16; m <<= 1) tm = fmaxf(tm, __shfl_xor(tm, m, 64));
      mnew[r] = fmaxf(mrow[r], tm);
      sc[r] = __expf(mrow[r] - mnew[r]);
      mrow[r] = mnew[r];
      tsum[r] = 0.f;
    }
#pragma unroll
    for (int jt = 0; jt < 4; ++jt)
#pragma unroll
      for (int r = 0; r < 4; ++r) {
        const float p = __expf(s[jt][r] - mnew[r]);
        s[jt][r] = p;
        tsum[r] += p;
      }
#pragma unroll
    for (int r = 0; r < 4; ++r) {
      float ts = tsum[r];
#pragma unroll
      for (int m = 1; m < 16; m <<= 1) ts += __shfl_xor(ts, m, 64);
      lrow[r] = lrow[r] * sc[r] + ts;
    }
#pragma unroll
    for (int db = 0; db < 4; ++db)
#pragma unroll
      for (int r = 0; r < 4; ++r) o[db][r] *= sc[r];
    // P -> LDS (bf16), C-layout -> A-layout redistribution
#pragma unroll
    for (int jt = 0; jt < 4; ++jt)
#pragma unroll
      for (int r = 0; r < 4; ++r)
        P[wave][rg * 4 + r][jt * 16 + fr] = f2bf(s[jt][r]);
    asm volatile("s_waitcnt lgkmcnt(0)" ::: "memory");  // intra-wave DS RAW fence
    // O += P * V
#pragma unroll
    for (int kb2 = 0; kb2 < 2; ++kb2) {
      const bf16x8 pa = *(const bf16x8*)&P[wave][fr][kb2 * 32 + fk];
      const u16* vp = vbh + (size_t)fr * 1024 + j0 + kb2 * 32 + fk;
#pragma unroll
      for (int db = 0; db < 4; ++db)
        o[db] = mfma16(pa, *(const bf16x8*)(vp + db * 16 * 1024), o[db]);
    }
  }
  // epilogue: divide by l, store bf16
#pragma unroll
  for (int r = 0; r < 4; ++r) {
    const float inv = 1.0f / lrow[r];
    u16* ap = att + (size_t)(b * 2048 + qrow0 + rg * 4 + r) * 768 + h * 64 + fr;
#pragma unroll
    for (int db = 0; db < 4; ++db)
      ap[db * 16] = f2bf(o[db][r] * inv);
  }
}

// ------------------------------------------------------------------ launch
extern "C" void kernel_launch(void* const* d_in, const int* in_sizes, int n_in,
                              void* d_out, int out_size, void* d_ws, size_t ws_size,
                              hipStream_t stream)
{
  const float* x     = (const float*)d_in[0];
  const float* tabx  = (const float*)d_in[1];
  const float* tab_g = (const float*)d_in[2];
  const float* tab_b = (const float*)d_in[3];
  const float* vid_g = (const float*)d_in[4];
  const float* vid_b = (const float*)d_in[5];
  const float* Wq    = (const float*)d_in[6];
  const float* Wk    = (const float*)d_in[7];
  const float* Wv    = (const float*)d_in[8];
  const float* q_g   = (const float*)d_in[9];
  const float* q_b   = (const float*)d_in[10];
  const float* k_g   = (const float*)d_in[11];
  const float* k_b   = (const float*)d_in[12];
  const float* Wo    = (const float*)d_in[13];
  const float* bo    = (const float*)d_in[14];

  // workspace layout (~94.4 MB peak; vT/att alias dead regions, stream-serial safe)
  char* ws = (char*)d_ws;
  const size_t O_WQT  = 0;
  const size_t O_WKT  = O_WQT  + (size_t)768 * 1024 * 2;
  const size_t O_WVT  = O_WKT  + (size_t)768 * 1024 * 2;
  const size_t O_WOT  = O_WVT  + (size_t)768 * 1024 * 2;
  const size_t O_XN   = O_WOT  + (size_t)1024 * 768 * 2;
  const size_t O_KVN  = O_XN   + (size_t)8192 * 1024 * 2;
  const size_t O_QPRE = O_KVN  + (size_t)4096 * 1024 * 2;
  const size_t O_KPRE = O_QPRE + (size_t)8192 * 768 * 4;
  const size_t O_QB   = O_KPRE + (size_t)4096 * 768 * 4;
  const size_t O_KB   = O_QB   + (size_t)8192 * 768 * 2;
  const size_t O_VB   = O_KB   + (size_t)4096 * 768 * 2;
  const size_t O_VT   = O_KPRE;   // alias: k_pre dead after its LN
  const size_t O_ATT  = O_QPRE;   // alias: q_pre dead after its LN

  u16*   WqT   = (u16*)(ws + O_WQT);
  u16*   WkT   = (u16*)(ws + O_WKT);
  u16*   WvT   = (u16*)(ws + O_WVT);
  u16*   WoT   = (u16*)(ws + O_WOT);
  u16*   xn    = (u16*)(ws + O_XN);
  u16*   kvn   = (u16*)(ws + O_KVN);
  float* q_pre = (float*)(ws + O_QPRE);
  float* k_pre = (float*)(ws + O_KPRE);
  u16*   qb    = (u16*)(ws + O_QB);
  u16*   kb    = (u16*)(ws + O_KB);
  u16*   vb    = (u16*)(ws + O_VB);
  u16*   vT    = (u16*)(ws + O_VT);
  u16*   attb  = (u16*)(ws + O_ATT);

  // 1) weights -> bf16, transposed to [N][K]
  transpose_w<<<dim3(32, 24), 256, 0, stream>>>(Wq, WqT, 1024, 768);
  transpose_w<<<dim3(32, 24), 256, 0, stream>>>(Wk, WkT, 1024, 768);
  transpose_w<<<dim3(32, 24), 256, 0, stream>>>(Wv, WvT, 1024, 768);
  transpose_w<<<dim3(24, 32), 256, 0, stream>>>(Wo, WoT, 768, 1024);
  // 2) input layernorms -> bf16
  ln_rows<<<4096, 256, 0, stream>>>(tabx, tab_g, tab_b, kvn, 1024, 1.0f);
  ln_rows<<<8192, 256, 0, stream>>>(x, vid_g, vid_b, xn, 1024, 1.0f);
  // 3) k path
  gemm_bt<0><<<dim3(32, 6), 256, 0, stream>>>(kvn, WkT, k_pre, nullptr, 4096, 768, 1024);
  ln_rows<<<4096, 256, 0, stream>>>(k_pre, k_g, k_b, kb, 768, 1.0f);
  // 4) v path (bf16 out, then transpose to [bh][d][j])
  gemm_bt<1><<<dim3(32, 6), 256, 0, stream>>>(kvn, WvT, vb, nullptr, 4096, 768, 1024);
  transpose_v<<<dim3(48, 16), 256, 0, stream>>>(vb, vT);
  // 5) q path (scale 1/sqrt(64) folded into LN epilogue)
  gemm_bt<0><<<dim3(64, 6), 256, 0, stream>>>(xn, WqT, q_pre, nullptr, 8192, 768, 1024);
  ln_rows<<<8192, 256, 0, stream>>>(q_pre, q_g, q_b, qb, 768, 0.125f);
  // 6) fused flash attention
  attn<<<dim3(48, 32), 256, 0, stream>>>(qb, kb, vT, attb);
  // 7) output projection + bias (fp32 out)
  gemm_bt<2><<<dim3(64, 8), 256, 0, stream>>>(attb, WoT, d_out, bo, 8192, 1024, 768);
}

// Round 2
// 247.542 us; speedup vs baseline: 1.3350x; 1.3350x over previous
//
#include <hip/hip_runtime.h>

typedef unsigned short u16;
typedef float  f32x4   __attribute__((ext_vector_type(4)));
typedef float  f32x16  __attribute__((ext_vector_type(16)));
typedef __bf16 bf16x8  __attribute__((ext_vector_type(8)));
typedef u16    u16x4   __attribute__((ext_vector_type(4)));

#define DEV __device__ __forceinline__

DEV u16 f2bf(float f) {                 // round-to-nearest-even f32 -> bf16 bits
  union { float f; unsigned u; } x; x.f = f;
  unsigned r = x.u + 0x7fffu + ((x.u >> 16) & 1u);
  return (u16)(r >> 16);
}

DEV unsigned cvtpk(float lo, float hi) { // packed bf16 pair: low16=lo, high16=hi (RNE)
  unsigned r;
  asm("v_cvt_pk_bf16_f32 %0, %1, %2" : "=v"(r) : "v"(lo), "v"(hi));
  return r;
}

DEV f32x4 mfma16(bf16x8 a, bf16x8 b, f32x4 c) {
  return __builtin_amdgcn_mfma_f32_16x16x32_bf16(a, b, c, 0, 0, 0);
}
DEV f32x16 mfma32(bf16x8 a, bf16x8 b, f32x16 c) {
  return __builtin_amdgcn_mfma_f32_32x32x16_bf16(a, b, c, 0, 0, 0);
}

DEV void gload16(const void* g, void* l) {   // async global->LDS, 16B/lane
  __builtin_amdgcn_global_load_lds(
      (__attribute__((address_space(1))) void*)g,
      (__attribute__((address_space(3))) void*)l, 16, 0, 0);
}

// ---------------------------------------------------------------- layernorm
__global__ void ln_rows(const float* __restrict__ x, const float* __restrict__ g,
                        const float* __restrict__ bta, u16* __restrict__ y,
                        int C, float outscale)
{
  const int row = blockIdx.x;
  const int tid = threadIdx.x;
  const int n4 = C >> 2;
  const float* xr = x + (size_t)row * C;
  f32x4 v = {0.f, 0.f, 0.f, 0.f};
  if (tid < n4) v = *(const f32x4*)(xr + 4 * tid);
  float s1 = v[0] + v[1] + v[2] + v[3];
  float s2 = v[0]*v[0] + v[1]*v[1] + v[2]*v[2] + v[3]*v[3];
#pragma unroll
  for (int o = 32; o > 0; o >>= 1) {
    s1 += __shfl_xor(s1, o, 64);
    s2 += __shfl_xor(s2, o, 64);
  }
  __shared__ float red[8];
  const int lane = tid & 63, wv = tid >> 6;
  if (lane == 0) { red[wv] = s1; red[4 + wv] = s2; }
  __syncthreads();
  s1 = red[0] + red[1] + red[2] + red[3];
  s2 = red[4] + red[5] + red[6] + red[7];
  const float mu = s1 / C;
  const float rs = rsqrtf(s2 / C - mu * mu + 1e-5f);
  if (tid < n4) {
    f32x4 gg = *(const f32x4*)(g + 4 * tid);
    f32x4 bb = *(const f32x4*)(bta + 4 * tid);
    u16x4 o4;
#pragma unroll
    for (int j = 0; j < 4; ++j)
      o4[j] = f2bf(((v[j] - mu) * rs * gg[j] + bb[j]) * outscale);
    *(u16x4*)(y + (size_t)row * C + 4 * tid) = o4;
  }
}

// ------------------------------------------------------- weight fp32 -> bf16^T
__global__ void transpose_w(const float* __restrict__ w, u16* __restrict__ wt,
                            int K, int N)
{
  __shared__ float t[32][33];
  const int k0 = blockIdx.x * 32, n0 = blockIdx.y * 32;
  const int tx = threadIdx.x & 31, ty = threadIdx.x >> 5;
#pragma unroll
  for (int i = ty; i < 32; i += 8)
    t[i][tx] = w[(size_t)(k0 + i) * N + n0 + tx];
  __syncthreads();
#pragma unroll
  for (int i = ty; i < 32; i += 8)
    wt[(size_t)(n0 + i) * K + k0 + tx] = f2bf(t[tx][i]);
}

// ------------------------------------------------------------- V transpose
__global__ void transpose_v(const u16* __restrict__ v, u16* __restrict__ vt)
{
  __shared__ u16 t[64][65];
  const int bh = blockIdx.x, b = bh / 12, h = bh - b * 12;
  const int j0 = blockIdx.y * 64;
  const int tx = threadIdx.x & 63, ty = threadIdx.x >> 6;
#pragma unroll
  for (int i = ty; i < 64; i += 4)
    t[i][tx] = v[(size_t)(b * 1024 + j0 + i) * 768 + h * 64 + tx];
  __syncthreads();
#pragma unroll
  for (int i = ty; i < 64; i += 4)
    vt[((size_t)bh * 64 + i) * 1024 + j0 + tx] = t[tx][i];
}

// ------------------------------------------------------------------- GEMM
// C[M][N] = A[M][K] * Bt[N][K]^T; MODE 0: fp32, 1: bf16, 2: fp32+bias.
template<int MODE>
__global__ __launch_bounds__(256)
void gemm_bt(const u16* __restrict__ A, const u16* __restrict__ Bt,
             void* __restrict__ Cp, const float* __restrict__ bias,
             int M, int N, int K)
{
  __shared__ __align__(16) u16 As[128 * 32];
  __shared__ __align__(16) u16 Bs[128 * 32];
  const int tid  = threadIdx.x;
  const int lane = tid & 63;
  const int wave = tid >> 6;
  const int bm = blockIdx.x * 128;
  const int bn = blockIdx.y * 128;
  const int wm = (wave >> 1) * 64;
  const int wn = (wave & 1) * 64;
  const int fr = lane & 15;
  const int fk = (lane >> 4) * 8;

  f32x4 acc[4][4] = {};

  const char* gA0 = (const char*)(A  + (size_t)bm * K);
  const char* gB0 = (const char*)(Bt + (size_t)bn * K);
  const int off0 = tid * 16;
  const size_t rowpitch = (size_t)K * 2;

  for (int k0 = 0; k0 < K; k0 += 32) {
#pragma unroll
    for (int c = 0; c < 2; ++c) {
      const int off  = off0 + c * 4096;
      const int row  = off >> 6;
      const int colb = off & 63;
      gload16(gA0 + (size_t)row * rowpitch + 2 * k0 + colb,
              (char*)As + wave * 1024 + c * 4096);
      gload16(gB0 + (size_t)row * rowpitch + 2 * k0 + colb,
              (char*)Bs + wave * 1024 + c * 4096);
    }
    __syncthreads();
    bf16x8 af[4], bg[4];
#pragma unroll
    for (int m = 0; m < 4; ++m)
      af[m] = *(const bf16x8*)&As[(wm + m * 16 + fr) * 32 + fk];
#pragma unroll
    for (int n = 0; n < 4; ++n)
      bg[n] = *(const bf16x8*)&Bs[(wn + n * 16 + fr) * 32 + fk];
#pragma unroll
    for (int m = 0; m < 4; ++m)
#pragma unroll
      for (int n = 0; n < 4; ++n)
        acc[m][n] = mfma16(af[m], bg[n], acc[m][n]);
    __syncthreads();
  }

  const int orow0 = bm + wm + 4 * (lane >> 4);
  const int ocol0 = bn + wn + fr;
#pragma unroll
  for (int m = 0; m < 4; ++m)
#pragma unroll
    for (int n = 0; n < 4; ++n)
#pragma unroll
      for (int r = 0; r < 4; ++r) {
        const int row = orow0 + m * 16 + r;
        const int col = ocol0 + n * 16;
        float v = acc[m][n][r];
        if (MODE == 2) v += bias[col];
        if (MODE == 1) ((u16*)Cp)[(size_t)row * N + col] = f2bf(v);
        else           ((float*)Cp)[(size_t)row * N + col] = v;
      }
}

// --------------------------------------------------------------- attention v2
// Swapped QK^T on 32x32x16 MFMA; softmax lane-local (q = lane&31), exp2-domain
// (log2e folded into q scale); P -> PV B-fragment via cvt_pk + permlane32_swap
// (no LDS in the main loop). 4 waves x 32 q-rows = 128 q/block; KVBLK=64.
// q[8192][768] (pre-scaled by 0.125*log2e), k[4096][768], vT[bh*64+d][1024].
__global__ __launch_bounds__(256)
void attn2(const u16* __restrict__ q, const u16* __restrict__ k,
           const u16* __restrict__ vT, u16* __restrict__ att)
{
  const int bh = blockIdx.x;
  const int b = bh / 12, h = bh - b * 12;
  const int tid = threadIdx.x, lane = tid & 63, wave = tid >> 6;
  const int lq  = lane & 31;            // this lane's q column (and K/V row idx)
  const int hi5 = lane >> 5;            // 0/1: k-half selector
  const int qrow = blockIdx.y * 128 + wave * 32 + lq;   // q row within batch b

  // Q as B-operand: n=q=lane&31, k-slice ds: d = ds*16 + hi5*8 + e
  const u16* qp = q + (size_t)(b * 2048 + qrow) * 768 + h * 64 + hi5 * 8;
  bf16x8 qf[4];
#pragma unroll
  for (int ds = 0; ds < 4; ++ds) qf[ds] = *(const bf16x8*)(qp + ds * 16);

  f32x16 ot0 = {}, ot1 = {};            // O^T tiles: rows d=db*32+.., col q
  float m = -1e30f, l = 0.f;

  const u16* kbase = k + (size_t)(b * 1024) * 768 + h * 64 + hi5 * 8;
  const u16* vbase = vT + ((size_t)bh * 64 + lq) * 1024 + hi5 * 8;

  for (int j0 = 0; j0 < 1024; j0 += 64) {
    // ---- S^T = K * Q^T : two 32x32 tiles (jt=0: j0..31, jt=1: j32..63)
    const u16* kr0 = kbase + (size_t)(j0 + lq) * 768;
    const u16* kr1 = kbase + (size_t)(j0 + 32 + lq) * 768;
    f32x16 st0 = {}, st1 = {};
#pragma unroll
    for (int ds = 0; ds < 4; ++ds) {
      st0 = mfma32(*(const bf16x8*)(kr0 + ds * 16), qf[ds], st0);
      st1 = mfma32(*(const bf16x8*)(kr1 + ds * 16), qf[ds], st1);
    }
    // ---- online softmax (exp2 domain), stats per q col: in-reg + 1 shuffle
    float ta0 = st0[0], ta1 = st0[1], ta2 = st0[2], ta3 = st0[3];
#pragma unroll
    for (int r = 4; r < 16; r += 4) {
      ta0 = fmaxf(ta0, st0[r]);     ta1 = fmaxf(ta1, st0[r + 1]);
      ta2 = fmaxf(ta2, st0[r + 2]); ta3 = fmaxf(ta3, st0[r + 3]);
    }
#pragma unroll
    for (int r = 0; r < 16; r += 4) {
      ta0 = fmaxf(ta0, st1[r]);     ta1 = fmaxf(ta1, st1[r + 1]);
      ta2 = fmaxf(ta2, st1[r + 2]); ta3 = fmaxf(ta3, st1[r + 3]);
    }
    float tmax = fmaxf(fmaxf(ta0, ta1), fmaxf(ta2, ta3));
    tmax = fmaxf(tmax, __shfl_xor(tmax, 32, 64));
    if (!__all(tmax - m <= 11.5416f)) {          // defer-max, THR = 8*log2e
      const float mn = fmaxf(m, tmax);
      const float sc = exp2f(m - mn);
      l *= sc;
#pragma unroll
      for (int r = 0; r < 16; ++r) { ot0[r] *= sc; ot1[r] *= sc; }
      m = mn;
    }
    float sa0 = 0.f, sa1 = 0.f, sa2 = 0.f, sa3 = 0.f;
#pragma unroll
    for (int r = 0; r < 16; r += 4) {
      float p0 = exp2f(st0[r]     - m); st0[r]     = p0; sa0 += p0;
      float p1 = exp2f(st0[r + 1] - m); st0[r + 1] = p1; sa1 += p1;
      float p2 = exp2f(st0[r + 2] - m); st0[r + 2] = p2; sa2 += p2;
      float p3 = exp2f(st0[r + 3] - m); st0[r + 3] = p3; sa3 += p3;
    }
#pragma unroll
    for (int r = 0; r < 16; r += 4) {
      float p0 = exp2f(st1[r]     - m); st1[r]     = p0; sa0 += p0;
      float p1 = exp2f(st1[r + 1] - m); st1[r + 1] = p1; sa1 += p1;
      float p2 = exp2f(st1[r + 2] - m); st1[r + 2] = p2; sa2 += p2;
      float p3 = exp2f(st1[r + 3] - m); st1[r + 3] = p3; sa3 += p3;
    }
    float ts = (sa0 + sa1) + (sa2 + sa3);
    ts += __shfl_xor(ts, 32, 64);
    l += ts;
    // ---- PV: per 16-j slice build B-fragment in-register, 2 mfma (d-blocks)
#pragma unroll
    for (int s4 = 0; s4 < 4; ++s4) {
      const int u = (s4 & 1) * 8;
      float a0, a1, a2, a3, b0, b1, b2, b3;
      if (s4 < 2) {
        a0 = st0[u]; a1 = st0[u + 1]; a2 = st0[u + 2]; a3 = st0[u + 3];
        b0 = st0[u + 4]; b1 = st0[u + 5]; b2 = st0[u + 6]; b3 = st0[u + 7];
      } else {
        a0 = st1[u]; a1 = st1[u + 1]; a2 = st1[u + 2]; a3 = st1[u + 3];
        b0 = st1[u + 4]; b1 = st1[u + 5]; b2 = st1[u + 6]; b3 = st1[u + 7];
      }
      const unsigned L0 = cvtpk(a0, a1), L1 = cvtpk(a2, a3);
      const unsigned H0 = cvtpk(b0, b1), H1 = cvtpk(b2, b3);
      const auto w02 = __builtin_amdgcn_permlane32_swap(L0, H0, false, false);
      const auto w13 = __builtin_amdgcn_permlane32_swap(L1, H1, false, false);
      union BU { unsigned w[4]; bf16x8 v; } pu;
      pu.w[0] = w02[0]; pu.w[1] = w13[0]; pu.w[2] = w02[1]; pu.w[3] = w13[1];
      const u16* vp = vbase + j0 + s4 * 16;
      ot0 = mfma32(*(const bf16x8*)vp, pu.v, ot0);
      ot1 = mfma32(*(const bf16x8*)(vp + 32 * 1024), pu.v, ot1);
    }
  }
  // ---- epilogue: normalize, transpose via LDS, coalesced store
  __shared__ __align__(16) u16 osm[4][32][72];
  const float inv = 1.0f / l;
#pragma unroll
  for (int r = 0; r < 16; ++r) {
    const int d0 = (r & 3) + 8 * (r >> 2) + 4 * hi5;
    osm[wave][lq][d0]      = f2bf(ot0[r] * inv);
    osm[wave][lq][32 + d0] = f2bf(ot1[r] * inv);
  }
  __syncthreads();
  const int col = (lane & 7) * 8;
#pragma unroll
  for (int pass = 0; pass < 4; ++pass) {
    const int row = pass * 8 + (lane >> 3);
    const bf16x8 vv = *(const bf16x8*)&osm[wave][row][col];
    const int qg = blockIdx.y * 128 + wave * 32 + row;
    *(bf16x8*)(att + (size_t)(b * 2048 + qg) * 768 + h * 64 + col) = vv;
  }
}

// ------------------------------------------------------------------ launch
extern "C" void kernel_launch(void* const* d_in, const int* in_sizes, int n_in,
                              void* d_out, int out_size, void* d_ws, size_t ws_size,
                              hipStream_t stream)
{
  const float* x     = (const float*)d_in[0];
  const float* tabx  = (const float*)d_in[1];
  const float* tab_g = (const float*)d_in[2];
  const float* tab_b = (const float*)d_in[3];
  const float* vid_g = (const float*)d_in[4];
  const float* vid_b = (const float*)d_in[5];
  const float* Wq    = (const float*)d_in[6];
  const float* Wk    = (const float*)d_in[7];
  const float* Wv    = (const float*)d_in[8];
  const float* q_g   = (const float*)d_in[9];
  const float* q_b   = (const float*)d_in[10];
  const float* k_g   = (const float*)d_in[11];
  const float* k_b   = (const float*)d_in[12];
  const float* Wo    = (const float*)d_in[13];
  const float* bo    = (const float*)d_in[14];

  char* ws = (char*)d_ws;
  const size_t O_WQT  = 0;
  const size_t O_WKT  = O_WQT  + (size_t)768 * 1024 * 2;
  const size_t O_WVT  = O_WKT  + (size_t)768 * 1024 * 2;
  const size_t O_WOT  = O_WVT  + (size_t)768 * 1024 * 2;
  const size_t O_XN   = O_WOT  + (size_t)1024 * 768 * 2;
  const size_t O_KVN  = O_XN   + (size_t)8192 * 1024 * 2;
  const size_t O_QPRE = O_KVN  + (size_t)4096 * 1024 * 2;
  const size_t O_KPRE = O_QPRE + (size_t)8192 * 768 * 4;
  const size_t O_QB   = O_KPRE + (size_t)4096 * 768 * 4;
  const size_t O_KB   = O_QB   + (size_t)8192 * 768 * 2;
  const size_t O_VB   = O_KB   + (size_t)4096 * 768 * 2;
  const size_t O_VT   = O_KPRE;   // alias: k_pre dead after its LN
  const size_t O_ATT  = O_QPRE;   // alias: q_pre dead after its LN

  u16*   WqT   = (u16*)(ws + O_WQT);
  u16*   WkT   = (u16*)(ws + O_WKT);
  u16*   WvT   = (u16*)(ws + O_WVT);
  u16*   WoT   = (u16*)(ws + O_WOT);
  u16*   xn    = (u16*)(ws + O_XN);
  u16*   kvn   = (u16*)(ws + O_KVN);
  float* q_pre = (float*)(ws + O_QPRE);
  float* k_pre = (float*)(ws + O_KPRE);
  u16*   qb    = (u16*)(ws + O_QB);
  u16*   kb    = (u16*)(ws + O_KB);
  u16*   vb    = (u16*)(ws + O_VB);
  u16*   vT    = (u16*)(ws + O_VT);
  u16*   attb  = (u16*)(ws + O_ATT);

  transpose_w<<<dim3(32, 24), 256, 0, stream>>>(Wq, WqT, 1024, 768);
  transpose_w<<<dim3(32, 24), 256, 0, stream>>>(Wk, WkT, 1024, 768);
  transpose_w<<<dim3(32, 24), 256, 0, stream>>>(Wv, WvT, 1024, 768);
  transpose_w<<<dim3(24, 32), 256, 0, stream>>>(Wo, WoT, 768, 1024);
  ln_rows<<<4096, 256, 0, stream>>>(tabx, tab_g, tab_b, kvn, 1024, 1.0f);
  ln_rows<<<8192, 256, 0, stream>>>(x, vid_g, vid_b, xn, 1024, 1.0f);
  gemm_bt<0><<<dim3(32, 6), 256, 0, stream>>>(kvn, WkT, k_pre, nullptr, 4096, 768, 1024);
  ln_rows<<<4096, 256, 0, stream>>>(k_pre, k_g, k_b, kb, 768, 1.0f);
  gemm_bt<1><<<dim3(32, 6), 256, 0, stream>>>(kvn, WvT, vb, nullptr, 4096, 768, 1024);
  transpose_v<<<dim3(48, 16), 256, 0, stream>>>(vb, vT);
  gemm_bt<0><<<dim3(64, 6), 256, 0, stream>>>(xn, WqT, q_pre, nullptr, 8192, 768, 1024);
  // q scale = (1/8) * log2(e): softmax computed in exp2 domain (exact same weights)
  ln_rows<<<8192, 256, 0, stream>>>(q_pre, q_g, q_b, qb, 768, 0.125f * 1.44269504089f);
  attn2<<<dim3(48, 16), 256, 0, stream>>>(qb, kb, vT, attb);
  gemm_bt<2><<<dim3(64, 8), 256, 0, stream>>>(attb, WoT, d_out, bo, 8192, 1024, 768);
}

// Round 3
// 227.428 us; speedup vs baseline: 1.4531x; 1.0884x over previous
//
#include <hip/hip_runtime.h>

typedef unsigned short u16;
typedef float  f32x4   __attribute__((ext_vector_type(4)));
typedef float  f32x16  __attribute__((ext_vector_type(16)));
typedef __bf16 bf16x8  __attribute__((ext_vector_type(8)));
typedef u16    u16x4   __attribute__((ext_vector_type(4)));

#define DEV __device__ __forceinline__

DEV u16 f2bf(float f) {                 // round-to-nearest-even f32 -> bf16 bits
  union { float f; unsigned u; } x; x.f = f;
  unsigned r = x.u + 0x7fffu + ((x.u >> 16) & 1u);
  return (u16)(r >> 16);
}

DEV unsigned cvtpk(float lo, float hi) { // packed bf16 pair: low16=lo, high16=hi (RNE)
  unsigned r;
  asm("v_cvt_pk_bf16_f32 %0, %1, %2" : "=v"(r) : "v"(lo), "v"(hi));
  return r;
}

DEV f32x4 mfma16(bf16x8 a, bf16x8 b, f32x4 c) {
  return __builtin_amdgcn_mfma_f32_16x16x32_bf16(a, b, c, 0, 0, 0);
}
DEV f32x16 mfma32(bf16x8 a, bf16x8 b, f32x16 c) {
  return __builtin_amdgcn_mfma_f32_32x32x16_bf16(a, b, c, 0, 0, 0);
}

DEV void gload16(const void* g, void* l) {   // async global->LDS, 16B/lane
  __builtin_amdgcn_global_load_lds(
      (__attribute__((address_space(1))) void*)g,
      (__attribute__((address_space(3))) void*)l, 16, 0, 0);
}

// ---------------------------------------------------------------- layernorm
__global__ void ln_rows(const float* __restrict__ x, const float* __restrict__ g,
                        const float* __restrict__ bta, u16* __restrict__ y,
                        int C, float outscale)
{
  const int row = blockIdx.x;
  const int tid = threadIdx.x;
  const int n4 = C >> 2;
  const float* xr = x + (size_t)row * C;
  f32x4 v = {0.f, 0.f, 0.f, 0.f};
  if (tid < n4) v = *(const f32x4*)(xr + 4 * tid);
  float s1 = v[0] + v[1] + v[2] + v[3];
  float s2 = v[0]*v[0] + v[1]*v[1] + v[2]*v[2] + v[3]*v[3];
#pragma unroll
  for (int o = 32; o > 0; o >>= 1) {
    s1 += __shfl_xor(s1, o, 64);
    s2 += __shfl_xor(s2, o, 64);
  }
  __shared__ float red[8];
  const int lane = tid & 63, wv = tid >> 6;
  if (lane == 0) { red[wv] = s1; red[4 + wv] = s2; }
  __syncthreads();
  s1 = red[0] + red[1] + red[2] + red[3];
  s2 = red[4] + red[5] + red[6] + red[7];
  const float mu = s1 / C;
  const float rs = rsqrtf(s2 / C - mu * mu + 1e-5f);
  if (tid < n4) {
    f32x4 gg = *(const f32x4*)(g + 4 * tid);
    f32x4 bb = *(const f32x4*)(bta + 4 * tid);
    u16x4 o4;
#pragma unroll
    for (int j = 0; j < 4; ++j)
      o4[j] = f2bf(((v[j] - mu) * rs * gg[j] + bb[j]) * outscale);
    *(u16x4*)(y + (size_t)row * C + 4 * tid) = o4;
  }
}

// ------------------------------------------------------- weight fp32 -> bf16^T
__global__ void transpose_w(const float* __restrict__ w, u16* __restrict__ wt,
                            int K, int N)
{
  __shared__ float t[32][33];
  const int k0 = blockIdx.x * 32, n0 = blockIdx.y * 32;
  const int tx = threadIdx.x & 31, ty = threadIdx.x >> 5;
#pragma unroll
  for (int i = ty; i < 32; i += 8)
    t[i][tx] = w[(size_t)(k0 + i) * N + n0 + tx];
  __syncthreads();
#pragma unroll
  for (int i = ty; i < 32; i += 8)
    wt[(size_t)(n0 + i) * K + k0 + tx] = f2bf(t[tx][i]);
}

// ------------------------------------------------------------- V transpose
__global__ void transpose_v(const u16* __restrict__ v, u16* __restrict__ vt)
{
  __shared__ u16 t[64][65];
  const int bh = blockIdx.x, b = bh / 12, h = bh - b * 12;
  const int j0 = blockIdx.y * 64;
  const int tx = threadIdx.x & 63, ty = threadIdx.x >> 6;
#pragma unroll
  for (int i = ty; i < 64; i += 4)
    t[i][tx] = v[(size_t)(b * 1024 + j0 + i) * 768 + h * 64 + tx];
  __syncthreads();
#pragma unroll
  for (int i = ty; i < 64; i += 4)
    vt[((size_t)bh * 64 + i) * 1024 + j0 + tx] = t[tx][i];
}

// ------------------------------------------------------------------- GEMM
// C[M][N] = A[M][K] * Bt[N][K]^T; occupancy-tuned tile: BM=64, BN=128, BK=64,
// 4 waves (2x2), wave tile 32x64, 16 MFMA/wave per K-step.
// MODE 0: fp32; MODE 1: bf16; MODE 2: fp32+bias; MODE 3: split k/v epilogue
//   (cols < 768 -> fp32 Cp pitch 768; cols >= 768 -> bf16 Cp2 pitch 768).
template<int MODE>
__global__ __launch_bounds__(256)
void gemm_bt(const u16* __restrict__ A, const u16* __restrict__ Bt,
             void* __restrict__ Cp, void* __restrict__ Cp2,
             const float* __restrict__ bias, int M, int N, int K)
{
  __shared__ __align__(16) u16 As[64 * 64];     // 8 KB
  __shared__ __align__(16) u16 Bs[128 * 64];    // 16 KB
  const int tid  = threadIdx.x;
  const int lane = tid & 63;
  const int wave = tid >> 6;
  const int bm = blockIdx.x * 64;
  const int bn = blockIdx.y * 128;
  const int wm = (wave >> 1) * 32;
  const int wn = (wave & 1) * 64;
  const int fr = lane & 15;
  const int fk = (lane >> 4) * 8;

  f32x4 acc[2][4] = {};

  const char* gA0 = (const char*)(A  + (size_t)bm * K);
  const char* gB0 = (const char*)(Bt + (size_t)bn * K);
  const size_t rowpitch = (size_t)K * 2;

  for (int k0 = 0; k0 < K; k0 += 64) {
    // A tile 64x64 bf16 = 8KB = 8 chunks of 1KB; wave stages chunks {w, w+4}
#pragma unroll
    for (int c = 0; c < 2; ++c) {
      const int off = tid * 16 + c * 4096;           // byte offset in tile
      gload16(gA0 + (size_t)(off >> 7) * rowpitch + 2 * k0 + (off & 127),
              (char*)As + wave * 1024 + c * 4096);
    }
    // B tile 128x64 = 16KB = 16 chunks; wave stages {w, w+4, w+8, w+12}
#pragma unroll
    for (int c = 0; c < 4; ++c) {
      const int off = tid * 16 + c * 4096;
      gload16(gB0 + (size_t)(off >> 7) * rowpitch + 2 * k0 + (off & 127),
              (char*)Bs + wave * 1024 + c * 4096);
    }
    __syncthreads();
    bf16x8 af[2][2], bg[4][2];
#pragma unroll
    for (int m = 0; m < 2; ++m)
#pragma unroll
      for (int kk = 0; kk < 2; ++kk)
        af[m][kk] = *(const bf16x8*)&As[(wm + m * 16 + fr) * 64 + kk * 32 + fk];
#pragma unroll
    for (int n = 0; n < 4; ++n)
#pragma unroll
      for (int kk = 0; kk < 2; ++kk)
        bg[n][kk] = *(const bf16x8*)&Bs[(wn + n * 16 + fr) * 64 + kk * 32 + fk];
#pragma unroll
    for (int kk = 0; kk < 2; ++kk)
#pragma unroll
      for (int m = 0; m < 2; ++m)
#pragma unroll
        for (int n = 0; n < 4; ++n)
          acc[m][n] = mfma16(af[m][kk], bg[n][kk], acc[m][n]);
    __syncthreads();
  }

  const int orow0 = bm + wm + 4 * (lane >> 4);
  const int ocol0 = bn + wn + fr;
#pragma unroll
  for (int m = 0; m < 2; ++m)
#pragma unroll
    for (int n = 0; n < 4; ++n)
#pragma unroll
      for (int r = 0; r < 4; ++r) {
        const int row = orow0 + m * 16 + r;
        const int col = ocol0 + n * 16;
        float v = acc[m][n][r];
        if (MODE == 2) v += bias[col];
        if (MODE == 3) {
          if (bn < 768) ((float*)Cp)[(size_t)row * 768 + col] = v;
          else          ((u16*)Cp2)[(size_t)row * 768 + (col - 768)] = f2bf(v);
        } else if (MODE == 1) {
          ((u16*)Cp)[(size_t)row * N + col] = f2bf(v);
        } else {
          ((float*)Cp)[(size_t)row * N + col] = v;
        }
      }
}

// --------------------------------------------------------------- attention v2
// Swapped QK^T on 32x32x16 MFMA; softmax lane-local (q = lane&31), exp2-domain
// (log2e folded into q scale); P -> PV B-fragment via cvt_pk + permlane32_swap.
__global__ __launch_bounds__(256)
void attn2(const u16* __restrict__ q, const u16* __restrict__ k,
           const u16* __restrict__ vT, u16* __restrict__ att)
{
  const int bh = blockIdx.x;
  const int b = bh / 12, h = bh - b * 12;
  const int tid = threadIdx.x, lane = tid & 63, wave = tid >> 6;
  const int lq  = lane & 31;
  const int hi5 = lane >> 5;
  const int qrow = blockIdx.y * 128 + wave * 32 + lq;

  const u16* qp = q + (size_t)(b * 2048 + qrow) * 768 + h * 64 + hi5 * 8;
  bf16x8 qf[4];
#pragma unroll
  for (int ds = 0; ds < 4; ++ds) qf[ds] = *(const bf16x8*)(qp + ds * 16);

  f32x16 ot0 = {}, ot1 = {};
  float m = -1e30f, l = 0.f;

  const u16* kbase = k + (size_t)(b * 1024) * 768 + h * 64 + hi5 * 8;
  const u16* vbase = vT + ((size_t)bh * 64 + lq) * 1024 + hi5 * 8;

  for (int j0 = 0; j0 < 1024; j0 += 64) {
    const u16* kr0 = kbase + (size_t)(j0 + lq) * 768;
    const u16* kr1 = kbase + (size_t)(j0 + 32 + lq) * 768;
    f32x16 st0 = {}, st1 = {};
    __builtin_amdgcn_s_setprio(1);
#pragma unroll
    for (int ds = 0; ds < 4; ++ds) {
      st0 = mfma32(*(const bf16x8*)(kr0 + ds * 16), qf[ds], st0);
      st1 = mfma32(*(const bf16x8*)(kr1 + ds * 16), qf[ds], st1);
    }
    __builtin_amdgcn_s_setprio(0);
    float ta0 = st0[0], ta1 = st0[1], ta2 = st0[2], ta3 = st0[3];
#pragma unroll
    for (int r = 4; r < 16; r += 4) {
      ta0 = fmaxf(ta0, st0[r]);     ta1 = fmaxf(ta1, st0[r + 1]);
      ta2 = fmaxf(ta2, st0[r + 2]); ta3 = fmaxf(ta3, st0[r + 3]);
    }
#pragma unroll
    for (int r = 0; r < 16; r += 4) {
      ta0 = fmaxf(ta0, st1[r]);     ta1 = fmaxf(ta1, st1[r + 1]);
      ta2 = fmaxf(ta2, st1[r + 2]); ta3 = fmaxf(ta3, st1[r + 3]);
    }
    float tmax = fmaxf(fmaxf(ta0, ta1), fmaxf(ta2, ta3));
    tmax = fmaxf(tmax, __shfl_xor(tmax, 32, 64));
    if (!__all(tmax - m <= 11.5416f)) {          // defer-max, THR = 8*log2e
      const float mn = fmaxf(m, tmax);
      const float sc = exp2f(m - mn);
      l *= sc;
#pragma unroll
      for (int r = 0; r < 16; ++r) { ot0[r] *= sc; ot1[r] *= sc; }
      m = mn;
    }
    float sa0 = 0.f, sa1 = 0.f, sa2 = 0.f, sa3 = 0.f;
#pragma unroll
    for (int r = 0; r < 16; r += 4) {
      float p0 = exp2f(st0[r]     - m); st0[r]     = p0; sa0 += p0;
      float p1 = exp2f(st0[r + 1] - m); st0[r + 1] = p1; sa1 += p1;
      float p2 = exp2f(st0[r + 2] - m); st0[r + 2] = p2; sa2 += p2;
      float p3 = exp2f(st0[r + 3] - m); st0[r + 3] = p3; sa3 += p3;
    }
#pragma unroll
    for (int r = 0; r < 16; r += 4) {
      float p0 = exp2f(st1[r]     - m); st1[r]     = p0; sa0 += p0;
      float p1 = exp2f(st1[r + 1] - m); st1[r + 1] = p1; sa1 += p1;
      float p2 = exp2f(st1[r + 2] - m); st1[r + 2] = p2; sa2 += p2;
      float p3 = exp2f(st1[r + 3] - m); st1[r + 3] = p3; sa3 += p3;
    }
    float ts = (sa0 + sa1) + (sa2 + sa3);
    ts += __shfl_xor(ts, 32, 64);
    l += ts;
    __builtin_amdgcn_s_setprio(1);
#pragma unroll
    for (int s4 = 0; s4 < 4; ++s4) {
      const int u = (s4 & 1) * 8;
      float a0, a1, a2, a3, b0, b1, b2, b3;
      if (s4 < 2) {
        a0 = st0[u]; a1 = st0[u + 1]; a2 = st0[u + 2]; a3 = st0[u + 3];
        b0 = st0[u + 4]; b1 = st0[u + 5]; b2 = st0[u + 6]; b3 = st0[u + 7];
      } else {
        a0 = st1[u]; a1 = st1[u + 1]; a2 = st1[u + 2]; a3 = st1[u + 3];
        b0 = st1[u + 4]; b1 = st1[u + 5]; b2 = st1[u + 6]; b3 = st1[u + 7];
      }
      const unsigned L0 = cvtpk(a0, a1), L1 = cvtpk(a2, a3);
      const unsigned H0 = cvtpk(b0, b1), H1 = cvtpk(b2, b3);
      const auto w02 = __builtin_amdgcn_permlane32_swap(L0, H0, false, false);
      const auto w13 = __builtin_amdgcn_permlane32_swap(L1, H1, false, false);
      union BU { unsigned w[4]; bf16x8 v; } pu;
      pu.w[0] = w02[0]; pu.w[1] = w13[0]; pu.w[2] = w02[1]; pu.w[3] = w13[1];
      const u16* vp = vbase + j0 + s4 * 16;
      ot0 = mfma32(*(const bf16x8*)vp, pu.v, ot0);
      ot1 = mfma32(*(const bf16x8*)(vp + 32 * 1024), pu.v, ot1);
    }
    __builtin_amdgcn_s_setprio(0);
  }
  __shared__ __align__(16) u16 osm[4][32][72];
  const float inv = 1.0f / l;
#pragma unroll
  for (int r = 0; r < 16; ++r) {
    const int d0 = (r & 3) + 8 * (r >> 2) + 4 * hi5;
    osm[wave][lq][d0]      = f2bf(ot0[r] * inv);
    osm[wave][lq][32 + d0] = f2bf(ot1[r] * inv);
  }
  __syncthreads();
  const int col = (lane & 7) * 8;
#pragma unroll
  for (int pass = 0; pass < 4; ++pass) {
    const int row = pass * 8 + (lane >> 3);
    const bf16x8 vv = *(const bf16x8*)&osm[wave][row][col];
    const int qg = blockIdx.y * 128 + wave * 32 + row;
    *(bf16x8*)(att + (size_t)(b * 2048 + qg) * 768 + h * 64 + col) = vv;
  }
}

// ------------------------------------------------------------------ launch
extern "C" void kernel_launch(void* const* d_in, const int* in_sizes, int n_in,
                              void* d_out, int out_size, void* d_ws, size_t ws_size,
                              hipStream_t stream)
{
  const float* x     = (const float*)d_in[0];
  const float* tabx  = (const float*)d_in[1];
  const float* tab_g = (const float*)d_in[2];
  const float* tab_b = (const float*)d_in[3];
  const float* vid_g = (const float*)d_in[4];
  const float* vid_b = (const float*)d_in[5];
  const float* Wq    = (const float*)d_in[6];
  const float* Wk    = (const float*)d_in[7];
  const float* Wv    = (const float*)d_in[8];
  const float* q_g   = (const float*)d_in[9];
  const float* q_b   = (const float*)d_in[10];
  const float* k_g   = (const float*)d_in[11];
  const float* k_b   = (const float*)d_in[12];
  const float* Wo    = (const float*)d_in[13];
  const float* bo    = (const float*)d_in[14];

  char* ws = (char*)d_ws;
  const size_t O_WQT  = 0;
  const size_t O_WKVT = O_WQT  + (size_t)768 * 1024 * 2;          // 1536x1024 (Wk rows 0-767, Wv rows 768-1535)
  const size_t O_WOT  = O_WKVT + (size_t)1536 * 1024 * 2;
  const size_t O_XN   = O_WOT  + (size_t)1024 * 768 * 2;
  const size_t O_KVN  = O_XN   + (size_t)8192 * 1024 * 2;
  const size_t O_QPRE = O_KVN  + (size_t)4096 * 1024 * 2;
  const size_t O_KPRE = O_QPRE + (size_t)8192 * 768 * 4;
  const size_t O_QB   = O_KPRE + (size_t)4096 * 768 * 4;
  const size_t O_KB   = O_QB   + (size_t)8192 * 768 * 2;
  const size_t O_VB   = O_KB   + (size_t)4096 * 768 * 2;
  const size_t O_VT   = O_KPRE;   // alias: k_pre dead after its LN
  const size_t O_ATT  = O_QPRE;   // alias: q_pre dead after its LN

  u16*   WqT   = (u16*)(ws + O_WQT);
  u16*   WkvT  = (u16*)(ws + O_WKVT);
  u16*   WoT   = (u16*)(ws + O_WOT);
  u16*   xn    = (u16*)(ws + O_XN);
  u16*   kvn   = (u16*)(ws + O_KVN);
  float* q_pre = (float*)(ws + O_QPRE);
  float* k_pre = (float*)(ws + O_KPRE);
  u16*   qb    = (u16*)(ws + O_QB);
  u16*   kb    = (u16*)(ws + O_KB);
  u16*   vb    = (u16*)(ws + O_VB);
  u16*   vT    = (u16*)(ws + O_VT);
  u16*   attb  = (u16*)(ws + O_ATT);

  transpose_w<<<dim3(32, 24), 256, 0, stream>>>(Wq, WqT, 1024, 768);
  transpose_w<<<dim3(32, 24), 256, 0, stream>>>(Wk, WkvT, 1024, 768);
  transpose_w<<<dim3(32, 24), 256, 0, stream>>>(Wv, WkvT + (size_t)768 * 1024, 1024, 768);
  transpose_w<<<dim3(24, 32), 256, 0, stream>>>(Wo, WoT, 768, 1024);
  ln_rows<<<4096, 256, 0, stream>>>(tabx, tab_g, tab_b, kvn, 1024, 1.0f);
  ln_rows<<<8192, 256, 0, stream>>>(x, vid_g, vid_b, xn, 1024, 1.0f);
  // merged k+v projection: N=1536, cols<768 -> k_pre (fp32), cols>=768 -> vb (bf16)
  gemm_bt<3><<<dim3(64, 12), 256, 0, stream>>>(kvn, WkvT, k_pre, vb, nullptr, 4096, 1536, 1024);
  ln_rows<<<4096, 256, 0, stream>>>(k_pre, k_g, k_b, kb, 768, 1.0f);
  transpose_v<<<dim3(48, 16), 256, 0, stream>>>(vb, vT);
  gemm_bt<0><<<dim3(128, 6), 256, 0, stream>>>(xn, WqT, q_pre, nullptr, nullptr, 8192, 768, 1024);
  // q scale = (1/8) * log2(e): softmax computed in exp2 domain
  ln_rows<<<8192, 256, 0, stream>>>(q_pre, q_g, q_b, qb, 768, 0.125f * 1.44269504089f);
  attn2<<<dim3(48, 16), 256, 0, stream>>>(qb, kb, vT, attb);
  gemm_bt<2><<<dim3(128, 8), 256, 0, stream>>>(attb, WoT, d_out, nullptr, bo, 8192, 1024, 768);
}

// Round 4
// 223.639 us; speedup vs baseline: 1.4777x; 1.0169x over previous
//
#include <hip/hip_runtime.h>

typedef unsigned short u16;
typedef float  f32x4   __attribute__((ext_vector_type(4)));
typedef float  f32x16  __attribute__((ext_vector_type(16)));
typedef __bf16 bf16x8  __attribute__((ext_vector_type(8)));
typedef u16    u16x4   __attribute__((ext_vector_type(4)));

#define DEV __device__ __forceinline__

DEV u16 f2bf(float f) {                 // round-to-nearest-even f32 -> bf16 bits
  union { float f; unsigned u; } x; x.f = f;
  unsigned r = x.u + 0x7fffu + ((x.u >> 16) & 1u);
  return (u16)(r >> 16);
}
DEV float bf2f(u16 b) { union { unsigned u; float f; } c; c.u = (unsigned)b << 16; return c.f; }

DEV unsigned cvtpk(float lo, float hi) { // packed bf16 pair: low16=lo, high16=hi (RNE)
  unsigned r;
  asm("v_cvt_pk_bf16_f32 %0, %1, %2" : "=v"(r) : "v"(lo), "v"(hi));
  return r;
}

DEV f32x4 mfma16(bf16x8 a, bf16x8 b, f32x4 c) {
  return __builtin_amdgcn_mfma_f32_16x16x32_bf16(a, b, c, 0, 0, 0);
}
DEV f32x16 mfma32(bf16x8 a, bf16x8 b, f32x16 c) {
  return __builtin_amdgcn_mfma_f32_32x32x16_bf16(a, b, c, 0, 0, 0);
}

DEV void gload16(const void* g, void* l) {   // async global->LDS, 16B/lane
  __builtin_amdgcn_global_load_lds(
      (__attribute__((address_space(1))) void*)g,
      (__attribute__((address_space(3))) void*)l, 16, 0, 0);
}

// ---------------------------------------------------------------- layernorm (fp32 in)
__global__ void ln_rows(const float* __restrict__ x, const float* __restrict__ g,
                        const float* __restrict__ bta, u16* __restrict__ y,
                        int C, float outscale)
{
  const int row = blockIdx.x;
  const int tid = threadIdx.x;
  const int n4 = C >> 2;
  const float* xr = x + (size_t)row * C;
  f32x4 v = {0.f, 0.f, 0.f, 0.f};
  if (tid < n4) v = *(const f32x4*)(xr + 4 * tid);
  float s1 = v[0] + v[1] + v[2] + v[3];
  float s2 = v[0]*v[0] + v[1]*v[1] + v[2]*v[2] + v[3]*v[3];
#pragma unroll
  for (int o = 32; o > 0; o >>= 1) {
    s1 += __shfl_xor(s1, o, 64);
    s2 += __shfl_xor(s2, o, 64);
  }
  __shared__ float red[8];
  const int lane = tid & 63, wv = tid >> 6;
  if (lane == 0) { red[wv] = s1; red[4 + wv] = s2; }
  __syncthreads();
  s1 = red[0] + red[1] + red[2] + red[3];
  s2 = red[4] + red[5] + red[6] + red[7];
  const float mu = s1 / C;
  const float rs = rsqrtf(s2 / C - mu * mu + 1e-5f);
  if (tid < n4) {
    f32x4 gg = *(const f32x4*)(g + 4 * tid);
    f32x4 bb = *(const f32x4*)(bta + 4 * tid);
    u16x4 o4;
#pragma unroll
    for (int j = 0; j < 4; ++j)
      o4[j] = f2bf(((v[j] - mu) * rs * gg[j] + bb[j]) * outscale);
    *(u16x4*)(y + (size_t)row * C + 4 * tid) = o4;
  }
}

// ---------------------------------------------------------------- layernorm (bf16 in)
__global__ void ln_rows_bf(const u16* __restrict__ x, const float* __restrict__ g,
                           const float* __restrict__ bta, u16* __restrict__ y,
                           int C, float outscale)
{
  const int row = blockIdx.x;
  const int tid = threadIdx.x;
  const int n4 = C >> 2;
  const u16* xr = x + (size_t)row * C;
  f32x4 v = {0.f, 0.f, 0.f, 0.f};
  if (tid < n4) {
    const u16x4 raw = *(const u16x4*)(xr + 4 * tid);
#pragma unroll
    for (int j = 0; j < 4; ++j) v[j] = bf2f(raw[j]);
  }
  float s1 = v[0] + v[1] + v[2] + v[3];
  float s2 = v[0]*v[0] + v[1]*v[1] + v[2]*v[2] + v[3]*v[3];
#pragma unroll
  for (int o = 32; o > 0; o >>= 1) {
    s1 += __shfl_xor(s1, o, 64);
    s2 += __shfl_xor(s2, o, 64);
  }
  __shared__ float red[8];
  const int lane = tid & 63, wv = tid >> 6;
  if (lane == 0) { red[wv] = s1; red[4 + wv] = s2; }
  __syncthreads();
  s1 = red[0] + red[1] + red[2] + red[3];
  s2 = red[4] + red[5] + red[6] + red[7];
  const float mu = s1 / C;
  const float rs = rsqrtf(s2 / C - mu * mu + 1e-5f);
  if (tid < n4) {
    f32x4 gg = *(const f32x4*)(g + 4 * tid);
    f32x4 bb = *(const f32x4*)(bta + 4 * tid);
    u16x4 o4;
#pragma unroll
    for (int j = 0; j < 4; ++j)
      o4[j] = f2bf(((v[j] - mu) * rs * gg[j] + bb[j]) * outscale);
    *(u16x4*)(y + (size_t)row * C + 4 * tid) = o4;
  }
}

// ------------------------------------------------------- weight fp32 -> bf16^T
__global__ void transpose_w(const float* __restrict__ w, u16* __restrict__ wt,
                            int K, int N)
{
  __shared__ float t[32][33];
  const int k0 = blockIdx.x * 32, n0 = blockIdx.y * 32;
  const int tx = threadIdx.x & 31, ty = threadIdx.x >> 5;
#pragma unroll
  for (int i = ty; i < 32; i += 8)
    t[i][tx] = w[(size_t)(k0 + i) * N + n0 + tx];
  __syncthreads();
#pragma unroll
  for (int i = ty; i < 32; i += 8)
    wt[(size_t)(n0 + i) * K + k0 + tx] = f2bf(t[tx][i]);
}

// ------------------------------------------------------------- V transpose
__global__ void transpose_v(const u16* __restrict__ v, u16* __restrict__ vt)
{
  __shared__ u16 t[64][65];
  const int bh = blockIdx.x, b = bh / 12, h = bh - b * 12;
  const int j0 = blockIdx.y * 64;
  const int tx = threadIdx.x & 63, ty = threadIdx.x >> 6;
#pragma unroll
  for (int i = ty; i < 64; i += 4)
    t[i][tx] = v[(size_t)(b * 1024 + j0 + i) * 768 + h * 64 + tx];
  __syncthreads();
#pragma unroll
  for (int i = ty; i < 64; i += 4)
    vt[((size_t)bh * 64 + i) * 1024 + j0 + tx] = t[tx][i];
}

// ------------------------------------------------------------------- GEMM
// C[M][N] = A[M][K] * Bt[N][K]^T; BM=64, BN=128, BK=64, 4 waves, wave 32x64.
// MODE 1: bf16 store; MODE 2: fp32+bias; MODE 3: split k/v epilogue
//   (cols < 768 -> bf16 Cp pitch 768; cols >= 768 -> bf16 Cp2 pitch 768).
template<int MODE>
__global__ __launch_bounds__(256)
void gemm_bt(const u16* __restrict__ A, const u16* __restrict__ Bt,
             void* __restrict__ Cp, void* __restrict__ Cp2,
             const float* __restrict__ bias, int M, int N, int K)
{
  __shared__ __align__(16) u16 As[64 * 64];     // 8 KB
  __shared__ __align__(16) u16 Bs[128 * 64];    // 16 KB
  const int tid  = threadIdx.x;
  const int lane = tid & 63;
  const int wave = tid >> 6;
  const int bm = blockIdx.x * 64;
  const int bn = blockIdx.y * 128;
  const int wm = (wave >> 1) * 32;
  const int wn = (wave & 1) * 64;
  const int fr = lane & 15;
  const int fk = (lane >> 4) * 8;

  f32x4 acc[2][4] = {};

  const char* gA0 = (const char*)(A  + (size_t)bm * K);
  const char* gB0 = (const char*)(Bt + (size_t)bn * K);
  const size_t rowpitch = (size_t)K * 2;

  for (int k0 = 0; k0 < K; k0 += 64) {
#pragma unroll
    for (int c = 0; c < 2; ++c) {
      const int off = tid * 16 + c * 4096;
      gload16(gA0 + (size_t)(off >> 7) * rowpitch + 2 * k0 + (off & 127),
              (char*)As + wave * 1024 + c * 4096);
    }
#pragma unroll
    for (int c = 0; c < 4; ++c) {
      const int off = tid * 16 + c * 4096;
      gload16(gB0 + (size_t)(off >> 7) * rowpitch + 2 * k0 + (off & 127),
              (char*)Bs + wave * 1024 + c * 4096);
    }
    __syncthreads();
    bf16x8 af[2][2], bg[4][2];
#pragma unroll
    for (int m = 0; m < 2; ++m)
#pragma unroll
      for (int kk = 0; kk < 2; ++kk)
        af[m][kk] = *(const bf16x8*)&As[(wm + m * 16 + fr) * 64 + kk * 32 + fk];
#pragma unroll
    for (int n = 0; n < 4; ++n)
#pragma unroll
      for (int kk = 0; kk < 2; ++kk)
        bg[n][kk] = *(const bf16x8*)&Bs[(wn + n * 16 + fr) * 64 + kk * 32 + fk];
#pragma unroll
    for (int kk = 0; kk < 2; ++kk)
#pragma unroll
      for (int m = 0; m < 2; ++m)
#pragma unroll
        for (int n = 0; n < 4; ++n)
          acc[m][n] = mfma16(af[m][kk], bg[n][kk], acc[m][n]);
    __syncthreads();
  }

  const int orow0 = bm + wm + 4 * (lane >> 4);
  const int ocol0 = bn + wn + fr;
#pragma unroll
  for (int m = 0; m < 2; ++m)
#pragma unroll
    for (int n = 0; n < 4; ++n)
#pragma unroll
      for (int r = 0; r < 4; ++r) {
        const int row = orow0 + m * 16 + r;
        const int col = ocol0 + n * 16;
        float v = acc[m][n][r];
        if (MODE == 2) v += bias[col];
        if (MODE == 3) {
          if (bn < 768) ((u16*)Cp)[(size_t)row * 768 + col] = f2bf(v);
          else          ((u16*)Cp2)[(size_t)row * 768 + (col - 768)] = f2bf(v);
        } else if (MODE == 1) {
          ((u16*)Cp)[(size_t)row * N + col] = f2bf(v);
        } else {
          ((float*)Cp)[(size_t)row * N + col] = v;
        }
      }
}

// --------------------------------------------------------------- attention v3
// Swapped QK^T on 32x32x16 MFMA; lane-local softmax (q = lane&31), exp2-domain;
// P -> PV B-fragment via cvt_pk + permlane32_swap; K/V register prefetch one
// j-tile ahead (K(t+1) issued after QK(t), V(t+1) after PV(t)).
__global__ __launch_bounds__(256, 3)
void attn2(const u16* __restrict__ q, const u16* __restrict__ k,
           const u16* __restrict__ vT, u16* __restrict__ att)
{
  const int bh = blockIdx.x;
  const int b = bh / 12, h = bh - b * 12;
  const int tid = threadIdx.x, lane = tid & 63, wave = tid >> 6;
  const int lq  = lane & 31;
  const int hi5 = lane >> 5;
  const int qrow = blockIdx.y * 128 + wave * 32 + lq;

  const u16* qp = q + (size_t)(b * 2048 + qrow) * 768 + h * 64 + hi5 * 8;
  bf16x8 qf[4];
#pragma unroll
  for (int ds = 0; ds < 4; ++ds) qf[ds] = *(const bf16x8*)(qp + ds * 16);

  f32x16 ot0 = {}, ot1 = {};
  float m = -1e30f, l = 0.f;

  const u16* kbase = k + (size_t)(b * 1024) * 768 + h * 64 + hi5 * 8;
  const u16* vbase = vT + ((size_t)bh * 64 + lq) * 1024 + hi5 * 8;

  bf16x8 ka[8];   // K regs: [ds] = row lq, [4+ds] = row lq+32
  bf16x8 va[8];   // V regs: [2*s4] = d-block0 row, [2*s4+1] = d-block1 row

  auto loadK = [&](int j0) {
    const u16* kr0 = kbase + (size_t)(j0 + lq) * 768;
    const u16* kr1 = kbase + (size_t)(j0 + 32 + lq) * 768;
#pragma unroll
    for (int ds = 0; ds < 4; ++ds) {
      ka[ds]     = *(const bf16x8*)(kr0 + ds * 16);
      ka[4 + ds] = *(const bf16x8*)(kr1 + ds * 16);
    }
  };
  auto loadV = [&](int j0) {
#pragma unroll
    for (int s4 = 0; s4 < 4; ++s4) {
      const u16* vp = vbase + j0 + s4 * 16;
      va[2 * s4]     = *(const bf16x8*)vp;
      va[2 * s4 + 1] = *(const bf16x8*)(vp + 32 * 1024);
    }
  };

  loadK(0);
  loadV(0);

  for (int j0 = 0; j0 < 1024; j0 += 64) {
    // ---- S^T = K * Q^T (uses prefetched ka)
    f32x16 st0 = {}, st1 = {};
    __builtin_amdgcn_s_setprio(1);
#pragma unroll
    for (int ds = 0; ds < 4; ++ds) {
      st0 = mfma32(ka[ds], qf[ds], st0);
      st1 = mfma32(ka[4 + ds], qf[ds], st1);
    }
    __builtin_amdgcn_s_setprio(0);
    if (j0 + 64 < 1024) loadK(j0 + 64);   // prefetch next K under softmax+PV
    // ---- online softmax (exp2 domain)
    float ta0 = st0[0], ta1 = st0[1], ta2 = st0[2], ta3 = st0[3];
#pragma unroll
    for (int r = 4; r < 16; r += 4) {
      ta0 = fmaxf(ta0, st0[r]);     ta1 = fmaxf(ta1, st0[r + 1]);
      ta2 = fmaxf(ta2, st0[r + 2]); ta3 = fmaxf(ta3, st0[r + 3]);
    }
#pragma unroll
    for (int r = 0; r < 16; r += 4) {
      ta0 = fmaxf(ta0, st1[r]);     ta1 = fmaxf(ta1, st1[r + 1]);
      ta2 = fmaxf(ta2, st1[r + 2]); ta3 = fmaxf(ta3, st1[r + 3]);
    }
    float tmax = fmaxf(fmaxf(ta0, ta1), fmaxf(ta2, ta3));
    tmax = fmaxf(tmax, __shfl_xor(tmax, 32, 64));
    if (!__all(tmax - m <= 11.5416f)) {          // defer-max, THR = 8*log2e
      const float mn = fmaxf(m, tmax);
      const float sc = exp2f(m - mn);
      l *= sc;
#pragma unroll
      for (int r = 0; r < 16; ++r) { ot0[r] *= sc; ot1[r] *= sc; }
      m = mn;
    }
    float sa0 = 0.f, sa1 = 0.f, sa2 = 0.f, sa3 = 0.f;
#pragma unroll
    for (int r = 0; r < 16; r += 4) {
      float p0 = exp2f(st0[r]     - m); st0[r]     = p0; sa0 += p0;
      float p1 = exp2f(st0[r + 1] - m); st0[r + 1] = p1; sa1 += p1;
      float p2 = exp2f(st0[r + 2] - m); st0[r + 2] = p2; sa2 += p2;
      float p3 = exp2f(st0[r + 3] - m); st0[r + 3] = p3; sa3 += p3;
    }
#pragma unroll
    for (int r = 0; r < 16; r += 4) {
      float p0 = exp2f(st1[r]     - m); st1[r]     = p0; sa0 += p0;
      float p1 = exp2f(st1[r + 1] - m); st1[r + 1] = p1; sa1 += p1;
      float p2 = exp2f(st1[r + 2] - m); st1[r + 2] = p2; sa2 += p2;
      float p3 = exp2f(st1[r + 3] - m); st1[r + 3] = p3; sa3 += p3;
    }
    float ts = (sa0 + sa1) + (sa2 + sa3);
    ts += __shfl_xor(ts, 32, 64);
    l += ts;
    // ---- PV (uses prefetched va)
    __builtin_amdgcn_s_setprio(1);
#pragma unroll
    for (int s4 = 0; s4 < 4; ++s4) {
      const int u = (s4 & 1) * 8;
      float a0, a1, a2, a3, b0, b1, b2, b3;
      if (s4 < 2) {
        a0 = st0[u]; a1 = st0[u + 1]; a2 = st0[u + 2]; a3 = st0[u + 3];
        b0 = st0[u + 4]; b1 = st0[u + 5]; b2 = st0[u + 6]; b3 = st0[u + 7];
      } else {
        a0 = st1[u]; a1 = st1[u + 1]; a2 = st1[u + 2]; a3 = st1[u + 3];
        b0 = st1[u + 4]; b1 = st1[u + 5]; b2 = st1[u + 6]; b3 = st1[u + 7];
      }
      const unsigned L0 = cvtpk(a0, a1), L1 = cvtpk(a2, a3);
      const unsigned H0 = cvtpk(b0, b1), H1 = cvtpk(b2, b3);
      const auto w02 = __builtin_amdgcn_permlane32_swap(L0, H0, false, false);
      const auto w13 = __builtin_amdgcn_permlane32_swap(L1, H1, false, false);
      union BU { unsigned w[4]; bf16x8 v; } pu;
      pu.w[0] = w02[0]; pu.w[1] = w13[0]; pu.w[2] = w02[1]; pu.w[3] = w13[1];
      ot0 = mfma32(va[2 * s4], pu.v, ot0);
      ot1 = mfma32(va[2 * s4 + 1], pu.v, ot1);
    }
    __builtin_amdgcn_s_setprio(0);
    if (j0 + 64 < 1024) loadV(j0 + 64);   // prefetch next V under next QK+softmax
  }
  // ---- epilogue: normalize, transpose via LDS, coalesced store
  __shared__ __align__(16) u16 osm[4][32][72];
  const float inv = 1.0f / l;
#pragma unroll
  for (int r = 0; r < 16; ++r) {
    const int d0 = (r & 3) + 8 * (r >> 2) + 4 * hi5;
    osm[wave][lq][d0]      = f2bf(ot0[r] * inv);
    osm[wave][lq][32 + d0] = f2bf(ot1[r] * inv);
  }
  __syncthreads();
  const int col = (lane & 7) * 8;
#pragma unroll
  for (int pass = 0; pass < 4; ++pass) {
    const int row = pass * 8 + (lane >> 3);
    const bf16x8 vv = *(const bf16x8*)&osm[wave][row][col];
    const int qg = blockIdx.y * 128 + wave * 32 + row;
    *(bf16x8*)(att + (size_t)(b * 2048 + qg) * 768 + h * 64 + col) = vv;
  }
}

// ------------------------------------------------------------------ launch
extern "C" void kernel_launch(void* const* d_in, const int* in_sizes, int n_in,
                              void* d_out, int out_size, void* d_ws, size_t ws_size,
                              hipStream_t stream)
{
  const float* x     = (const float*)d_in[0];
  const float* tabx  = (const float*)d_in[1];
  const float* tab_g = (const float*)d_in[2];
  const float* tab_b = (const float*)d_in[3];
  const float* vid_g = (const float*)d_in[4];
  const float* vid_b = (const float*)d_in[5];
  const float* Wq    = (const float*)d_in[6];
  const float* Wk    = (const float*)d_in[7];
  const float* Wv    = (const float*)d_in[8];
  const float* q_g   = (const float*)d_in[9];
  const float* q_b   = (const float*)d_in[10];
  const float* k_g   = (const float*)d_in[11];
  const float* k_b   = (const float*)d_in[12];
  const float* Wo    = (const float*)d_in[13];
  const float* bo    = (const float*)d_in[14];

  char* ws = (char*)d_ws;
  const size_t O_WQT  = 0;
  const size_t O_WKVT = O_WQT  + (size_t)768 * 1024 * 2;   // 1536x1024 (Wk | Wv)
  const size_t O_WOT  = O_WKVT + (size_t)1536 * 1024 * 2;
  const size_t O_XN   = O_WOT  + (size_t)1024 * 768 * 2;
  const size_t O_KVN  = O_XN   + (size_t)8192 * 1024 * 2;
  const size_t O_QPRE = O_KVN  + (size_t)4096 * 1024 * 2;  // bf16 now
  const size_t O_KPRE = O_QPRE + (size_t)8192 * 768 * 2;   // bf16 now
  const size_t O_QB   = O_KPRE + (size_t)4096 * 768 * 2;
  const size_t O_KB   = O_QB   + (size_t)8192 * 768 * 2;
  const size_t O_VB   = O_KB   + (size_t)4096 * 768 * 2;
  const size_t O_VT   = O_VB   + (size_t)4096 * 768 * 2;
  const size_t O_ATT  = O_QPRE;   // alias: q_pre dead after its LN

  u16*   WqT   = (u16*)(ws + O_WQT);
  u16*   WkvT  = (u16*)(ws + O_WKVT);
  u16*   WoT   = (u16*)(ws + O_WOT);
  u16*   xn    = (u16*)(ws + O_XN);
  u16*   kvn   = (u16*)(ws + O_KVN);
  u16*   q_pre = (u16*)(ws + O_QPRE);
  u16*   k_pre = (u16*)(ws + O_KPRE);
  u16*   qb    = (u16*)(ws + O_QB);
  u16*   kb    = (u16*)(ws + O_KB);
  u16*   vb    = (u16*)(ws + O_VB);
  u16*   vT    = (u16*)(ws + O_VT);
  u16*   attb  = (u16*)(ws + O_ATT);

  transpose_w<<<dim3(32, 24), 256, 0, stream>>>(Wq, WqT, 1024, 768);
  transpose_w<<<dim3(32, 24), 256, 0, stream>>>(Wk, WkvT, 1024, 768);
  transpose_w<<<dim3(32, 24), 256, 0, stream>>>(Wv, WkvT + (size_t)768 * 1024, 1024, 768);
  transpose_w<<<dim3(24, 32), 256, 0, stream>>>(Wo, WoT, 768, 1024);
  ln_rows<<<4096, 256, 0, stream>>>(tabx, tab_g, tab_b, kvn, 1024, 1.0f);
  ln_rows<<<8192, 256, 0, stream>>>(x, vid_g, vid_b, xn, 1024, 1.0f);
  // merged k+v projection: N=1536, cols<768 -> k_pre (bf16), cols>=768 -> vb (bf16)
  gemm_bt<3><<<dim3(64, 12), 256, 0, stream>>>(kvn, WkvT, k_pre, vb, nullptr, 4096, 1536, 1024);
  ln_rows_bf<<<4096, 256, 0, stream>>>(k_pre, k_g, k_b, kb, 768, 1.0f);
  transpose_v<<<dim3(48, 16), 256, 0, stream>>>(vb, vT);
  gemm_bt<1><<<dim3(128, 6), 256, 0, stream>>>(xn, WqT, q_pre, nullptr, nullptr, 8192, 768, 1024);
  // q scale = (1/8) * log2(e): softmax computed in exp2 domain
  ln_rows_bf<<<8192, 256, 0, stream>>>(q_pre, q_g, q_b, qb, 768, 0.125f * 1.44269504089f);
  attn2<<<dim3(48, 16), 256, 0, stream>>>(qb, kb, vT, attb);
  gemm_bt<2><<<dim3(128, 8), 256, 0, stream>>>(attb, WoT, d_out, nullptr, bo, 8192, 1024, 768);
}

// Round 5
// 178.907 us; speedup vs baseline: 1.8472x; 1.2500x over previous
//
#include <hip/hip_runtime.h>

typedef unsigned short u16;
typedef float  f32x4   __attribute__((ext_vector_type(4)));
typedef float  f32x16  __attribute__((ext_vector_type(16)));
typedef __bf16 bf16x8  __attribute__((ext_vector_type(8)));
typedef u16    u16x4   __attribute__((ext_vector_type(4)));

#define DEV __device__ __forceinline__

DEV u16 f2bf(float f) {                 // round-to-nearest-even f32 -> bf16 bits
  union { float f; unsigned u; } x; x.f = f;
  unsigned r = x.u + 0x7fffu + ((x.u >> 16) & 1u);
  return (u16)(r >> 16);
}
DEV float bf2f(u16 b) { union { unsigned u; float f; } c; c.u = (unsigned)b << 16; return c.f; }

DEV unsigned cvtpk(float lo, float hi) { // packed bf16 pair: low16=lo, high16=hi (RNE)
  unsigned r;
  asm("v_cvt_pk_bf16_f32 %0, %1, %2" : "=v"(r) : "v"(lo), "v"(hi));
  return r;
}

DEV f32x4 mfma16(bf16x8 a, bf16x8 b, f32x4 c) {
  return __builtin_amdgcn_mfma_f32_16x16x32_bf16(a, b, c, 0, 0, 0);
}
DEV f32x16 mfma32(bf16x8 a, bf16x8 b, f32x16 c) {
  return __builtin_amdgcn_mfma_f32_32x32x16_bf16(a, b, c, 0, 0, 0);
}

DEV void gload16(const void* g, void* l) {   // async global->LDS, 16B/lane
  __builtin_amdgcn_global_load_lds(
      (__attribute__((address_space(1))) void*)g,
      (__attribute__((address_space(3))) void*)l, 16, 0, 0);
}

// ---------------------------------------------------------------- layernorm (fp32 in)
__global__ void ln_rows(const float* __restrict__ x, const float* __restrict__ g,
                        const float* __restrict__ bta, u16* __restrict__ y,
                        int C, float outscale)
{
  const int row = blockIdx.x;
  const int tid = threadIdx.x;
  const int n4 = C >> 2;
  const float* xr = x + (size_t)row * C;
  f32x4 v = {0.f, 0.f, 0.f, 0.f};
  if (tid < n4) v = *(const f32x4*)(xr + 4 * tid);
  float s1 = v[0] + v[1] + v[2] + v[3];
  float s2 = v[0]*v[0] + v[1]*v[1] + v[2]*v[2] + v[3]*v[3];
#pragma unroll
  for (int o = 32; o > 0; o >>= 1) {
    s1 += __shfl_xor(s1, o, 64);
    s2 += __shfl_xor(s2, o, 64);
  }
  __shared__ float red[8];
  const int lane = tid & 63, wv = tid >> 6;
  if (lane == 0) { red[wv] = s1; red[4 + wv] = s2; }
  __syncthreads();
  s1 = red[0] + red[1] + red[2] + red[3];
  s2 = red[4] + red[5] + red[6] + red[7];
  const float mu = s1 / C;
  const float rs = rsqrtf(s2 / C - mu * mu + 1e-5f);
  if (tid < n4) {
    f32x4 gg = *(const f32x4*)(g + 4 * tid);
    f32x4 bb = *(const f32x4*)(bta + 4 * tid);
    u16x4 o4;
#pragma unroll
    for (int j = 0; j < 4; ++j)
      o4[j] = f2bf(((v[j] - mu) * rs * gg[j] + bb[j]) * outscale);
    *(u16x4*)(y + (size_t)row * C + 4 * tid) = o4;
  }
}

// ---------------------------------------------------------------- layernorm (bf16 in)
__global__ void ln_rows_bf(const u16* __restrict__ x, const float* __restrict__ g,
                           const float* __restrict__ bta, u16* __restrict__ y,
                           int C, float outscale)
{
  const int row = blockIdx.x;
  const int tid = threadIdx.x;
  const int n4 = C >> 2;
  const u16* xr = x + (size_t)row * C;
  f32x4 v = {0.f, 0.f, 0.f, 0.f};
  if (tid < n4) {
    const u16x4 raw = *(const u16x4*)(xr + 4 * tid);
#pragma unroll
    for (int j = 0; j < 4; ++j) v[j] = bf2f(raw[j]);
  }
  float s1 = v[0] + v[1] + v[2] + v[3];
  float s2 = v[0]*v[0] + v[1]*v[1] + v[2]*v[2] + v[3]*v[3];
#pragma unroll
  for (int o = 32; o > 0; o >>= 1) {
    s1 += __shfl_xor(s1, o, 64);
    s2 += __shfl_xor(s2, o, 64);
  }
  __shared__ float red[8];
  const int lane = tid & 63, wv = tid >> 6;
  if (lane == 0) { red[wv] = s1; red[4 + wv] = s2; }
  __syncthreads();
  s1 = red[0] + red[1] + red[2] + red[3];
  s2 = red[4] + red[5] + red[6] + red[7];
  const float mu = s1 / C;
  const float rs = rsqrtf(s2 / C - mu * mu + 1e-5f);
  if (tid < n4) {
    f32x4 gg = *(const f32x4*)(g + 4 * tid);
    f32x4 bb = *(const f32x4*)(bta + 4 * tid);
    u16x4 o4;
#pragma unroll
    for (int j = 0; j < 4; ++j)
      o4[j] = f2bf(((v[j] - mu) * rs * gg[j] + bb[j]) * outscale);
    *(u16x4*)(y + (size_t)row * C + 4 * tid) = o4;
  }
}

// ------------------------------------------------------- weight fp32 -> bf16^T
__global__ void transpose_w(const float* __restrict__ w, u16* __restrict__ wt,
                            int K, int N)
{
  __shared__ float t[32][33];
  const int k0 = blockIdx.x * 32, n0 = blockIdx.y * 32;
  const int tx = threadIdx.x & 31, ty = threadIdx.x >> 5;
#pragma unroll
  for (int i = ty; i < 32; i += 8)
    t[i][tx] = w[(size_t)(k0 + i) * N + n0 + tx];
  __syncthreads();
#pragma unroll
  for (int i = ty; i < 32; i += 8)
    wt[(size_t)(n0 + i) * K + k0 + tx] = f2bf(t[tx][i]);
}

// ------------------------------------------------------------- V transpose
__global__ void transpose_v(const u16* __restrict__ v, u16* __restrict__ vt)
{
  __shared__ u16 t[64][65];
  const int bh = blockIdx.x, b = bh / 12, h = bh - b * 12;
  const int j0 = blockIdx.y * 64;
  const int tx = threadIdx.x & 63, ty = threadIdx.x >> 6;
#pragma unroll
  for (int i = ty; i < 64; i += 4)
    t[i][tx] = v[(size_t)(b * 1024 + j0 + i) * 768 + h * 64 + tx];
  __syncthreads();
#pragma unroll
  for (int i = ty; i < 64; i += 4)
    vt[((size_t)bh * 64 + i) * 1024 + j0 + tx] = t[tx][i];
}

// ------------------------------------------------------------------- GEMM
// C[M][N] = A[M][K] * Bt[N][K]^T; BM=64, BN=128, BK=64, 4 waves, wave 32x64.
// MODE 1: bf16 store; MODE 2: fp32+bias; MODE 3: split k/v epilogue
//   (cols < 768 -> bf16 Cp pitch 768; cols >= 768 -> bf16 Cp2 pitch 768).
template<int MODE>
__global__ __launch_bounds__(256)
void gemm_bt(const u16* __restrict__ A, const u16* __restrict__ Bt,
             void* __restrict__ Cp, void* __restrict__ Cp2,
             const float* __restrict__ bias, int M, int N, int K)
{
  __shared__ __align__(16) u16 As[64 * 64];     // 8 KB
  __shared__ __align__(16) u16 Bs[128 * 64];    // 16 KB
  const int tid  = threadIdx.x;
  const int lane = tid & 63;
  const int wave = tid >> 6;
  const int bm = blockIdx.x * 64;
  const int bn = blockIdx.y * 128;
  const int wm = (wave >> 1) * 32;
  const int wn = (wave & 1) * 64;
  const int fr = lane & 15;
  const int fk = (lane >> 4) * 8;

  f32x4 acc[2][4] = {};

  const char* gA0 = (const char*)(A  + (size_t)bm * K);
  const char* gB0 = (const char*)(Bt + (size_t)bn * K);
  const size_t rowpitch = (size_t)K * 2;

  for (int k0 = 0; k0 < K; k0 += 64) {
#pragma unroll
    for (int c = 0; c < 2; ++c) {
      const int off = tid * 16 + c * 4096;
      gload16(gA0 + (size_t)(off >> 7) * rowpitch + 2 * k0 + (off & 127),
              (char*)As + wave * 1024 + c * 4096);
    }
#pragma unroll
    for (int c = 0; c < 4; ++c) {
      const int off = tid * 16 + c * 4096;
      gload16(gB0 + (size_t)(off >> 7) * rowpitch + 2 * k0 + (off & 127),
              (char*)Bs + wave * 1024 + c * 4096);
    }
    __syncthreads();
    bf16x8 af[2][2], bg[4][2];
#pragma unroll
    for (int m = 0; m < 2; ++m)
#pragma unroll
      for (int kk = 0; kk < 2; ++kk)
        af[m][kk] = *(const bf16x8*)&As[(wm + m * 16 + fr) * 64 + kk * 32 + fk];
#pragma unroll
    for (int n = 0; n < 4; ++n)
#pragma unroll
      for (int kk = 0; kk < 2; ++kk)
        bg[n][kk] = *(const bf16x8*)&Bs[(wn + n * 16 + fr) * 64 + kk * 32 + fk];
#pragma unroll
    for (int kk = 0; kk < 2; ++kk)
#pragma unroll
      for (int m = 0; m < 2; ++m)
#pragma unroll
        for (int n = 0; n < 4; ++n)
          acc[m][n] = mfma16(af[m][kk], bg[n][kk], acc[m][n]);
    __syncthreads();
  }

  const int orow0 = bm + wm + 4 * (lane >> 4);
  const int ocol0 = bn + wn + fr;
#pragma unroll
  for (int m = 0; m < 2; ++m)
#pragma unroll
    for (int n = 0; n < 4; ++n)
#pragma unroll
      for (int r = 0; r < 4; ++r) {
        const int row = orow0 + m * 16 + r;
        const int col = ocol0 + n * 16;
        float v = acc[m][n][r];
        if (MODE == 2) v += bias[col];
        if (MODE == 3) {
          if (bn < 768) ((u16*)Cp)[(size_t)row * 768 + col] = f2bf(v);
          else          ((u16*)Cp2)[(size_t)row * 768 + (col - 768)] = f2bf(v);
        } else if (MODE == 1) {
          ((u16*)Cp)[(size_t)row * N + col] = f2bf(v);
        } else {
          ((float*)Cp)[(size_t)row * N + col] = v;
        }
      }
}

// --------------------------------------------------------------- attention v4
// Swapped QK^T on 32x32x16 MFMA; lane-local softmax (q = lane&31), exp2-domain;
// P -> PV B-fragment via cvt_pk + permlane32_swap.
// K/V tiles staged in LDS per block (coalesced global_load_lds, shared by all
// 4 waves) with T2-style XOR swizzle: linear LDS dest + inverse-swizzled
// global source + swizzled ds_read (rule #21).
__global__ __launch_bounds__(256, 3)
void attn3(const u16* __restrict__ q, const u16* __restrict__ k,
           const u16* __restrict__ vT, u16* __restrict__ att)
{
  __shared__ __align__(16) u16 Ks[64 * 64];     // 8 KB: K tile [j][d]
  __shared__ __align__(16) u16 Vs[64 * 64];     // 8 KB: V tile [d][j]
  __shared__ __align__(16) u16 osm[4][32][72];  // epilogue transpose

  const int bh = blockIdx.x;
  const int b = bh / 12, h = bh - b * 12;
  const int tid = threadIdx.x, lane = tid & 63, wave = tid >> 6;
  const int lq  = lane & 31;
  const int hi5 = lane >> 5;
  const int qrow = blockIdx.y * 128 + wave * 32 + lq;

  const u16* qp = q + (size_t)(b * 2048 + qrow) * 768 + h * 64 + hi5 * 8;
  bf16x8 qf[4];
#pragma unroll
  for (int ds = 0; ds < 4; ++ds) qf[ds] = *(const bf16x8*)(qp + ds * 16);

  f32x16 ot0 = {}, ot1 = {};
  float m = -1e30f, l = 0.f;

  // global byte bases
  const char* kg = (const char*)k + (size_t)(b * 1024) * 1536 + h * 128;
  const char* vg = (const char*)vT + (size_t)bh * 64 * 2048;

  // swizzled read offsets (within a 128B row: byte ^= (row&7)<<4)
  const int rsw0 = (lq & 7) << 4;

  for (int j0 = 0; j0 < 1024; j0 += 64) {
    // ---- stage K[64][64] and V[64][64] (8KB each), source pre-swizzled
#pragma unroll
    for (int c = 0; c < 2; ++c) {
      const int o   = tid * 16 + c * 4096;
      const int row = o >> 7;
      const int scol = (o & 127) ^ ((row & 7) << 4);
      gload16(kg + (size_t)(j0 + row) * 1536 + scol,
              (char*)Ks + wave * 1024 + c * 4096);
      gload16(vg + (size_t)row * 2048 + j0 * 2 + scol,
              (char*)Vs + wave * 1024 + c * 4096);
    }
    __syncthreads();                       // drains vmcnt -> tiles ready
    // ---- S^T = K * Q^T
    f32x16 st0 = {}, st1 = {};
    __builtin_amdgcn_s_setprio(1);
#pragma unroll
    for (int ds = 0; ds < 4; ++ds) {
      const int cb = ds * 32 + hi5 * 16;
      const bf16x8 k0 = *(const bf16x8*)((const char*)Ks + lq * 128 + (cb ^ rsw0));
      const bf16x8 k1 = *(const bf16x8*)((const char*)Ks + (lq + 32) * 128 + (cb ^ rsw0));
      st0 = mfma32(k0, qf[ds], st0);
      st1 = mfma32(k1, qf[ds], st1);
    }
    __builtin_amdgcn_s_setprio(0);
    // ---- online softmax (exp2 domain)
    float ta0 = st0[0], ta1 = st0[1], ta2 = st0[2], ta3 = st0[3];
#pragma unroll
    for (int r = 4; r < 16; r += 4) {
      ta0 = fmaxf(ta0, st0[r]);     ta1 = fmaxf(ta1, st0[r + 1]);
      ta2 = fmaxf(ta2, st0[r + 2]); ta3 = fmaxf(ta3, st0[r + 3]);
    }
#pragma unroll
    for (int r = 0; r < 16; r += 4) {
      ta0 = fmaxf(ta0, st1[r]);     ta1 = fmaxf(ta1, st1[r + 1]);
      ta2 = fmaxf(ta2, st1[r + 2]); ta3 = fmaxf(ta3, st1[r + 3]);
    }
    float tmax = fmaxf(fmaxf(ta0, ta1), fmaxf(ta2, ta3));
    tmax = fmaxf(tmax, __shfl_xor(tmax, 32, 64));
    if (!__all(tmax - m <= 11.5416f)) {          // defer-max, THR = 8*log2e
      const float mn = fmaxf(m, tmax);
      const float sc = exp2f(m - mn);
      l *= sc;
#pragma unroll
      for (int r = 0; r < 16; ++r) { ot0[r] *= sc; ot1[r] *= sc; }
      m = mn;
    }
    float sa0 = 0.f, sa1 = 0.f, sa2 = 0.f, sa3 = 0.f;
#pragma unroll
    for (int r = 0; r < 16; r += 4) {
      float p0 = exp2f(st0[r]     - m); st0[r]     = p0; sa0 += p0;
      float p1 = exp2f(st0[r + 1] - m); st0[r + 1] = p1; sa1 += p1;
      float p2 = exp2f(st0[r + 2] - m); st0[r + 2] = p2; sa2 += p2;
      float p3 = exp2f(st0[r + 3] - m); st0[r + 3] = p3; sa3 += p3;
    }
#pragma unroll
    for (int r = 0; r < 16; r += 4) {
      float p0 = exp2f(st1[r]     - m); st1[r]     = p0; sa0 += p0;
      float p1 = exp2f(st1[r + 1] - m); st1[r + 1] = p1; sa1 += p1;
      float p2 = exp2f(st1[r + 2] - m); st1[r + 2] = p2; sa2 += p2;
      float p3 = exp2f(st1[r + 3] - m); st1[r + 3] = p3; sa3 += p3;
    }
    float ts = (sa0 + sa1) + (sa2 + sa3);
    ts += __shfl_xor(ts, 32, 64);
    l += ts;
    // ---- PV
    __builtin_amdgcn_s_setprio(1);
#pragma unroll
    for (int s4 = 0; s4 < 4; ++s4) {
      const int u = (s4 & 1) * 8;
      float a0, a1, a2, a3, b0, b1, b2, b3;
      if (s4 < 2) {
        a0 = st0[u]; a1 = st0[u + 1]; a2 = st0[u + 2]; a3 = st0[u + 3];
        b0 = st0[u + 4]; b1 = st0[u + 5]; b2 = st0[u + 6]; b3 = st0[u + 7];
      } else {
        a0 = st1[u]; a1 = st1[u + 1]; a2 = st1[u + 2]; a3 = st1[u + 3];
        b0 = st1[u + 4]; b1 = st1[u + 5]; b2 = st1[u + 6]; b3 = st1[u + 7];
      }
      const unsigned L0 = cvtpk(a0, a1), L1 = cvtpk(a2, a3);
      const unsigned H0 = cvtpk(b0, b1), H1 = cvtpk(b2, b3);
      const auto w02 = __builtin_amdgcn_permlane32_swap(L0, H0, false, false);
      const auto w13 = __builtin_amdgcn_permlane32_swap(L1, H1, false, false);
      union BU { unsigned w[4]; bf16x8 v; } pu;
      pu.w[0] = w02[0]; pu.w[1] = w13[0]; pu.w[2] = w02[1]; pu.w[3] = w13[1];
      const int cb = s4 * 32 + hi5 * 16;
      const bf16x8 v0 = *(const bf16x8*)((const char*)Vs + lq * 128 + (cb ^ rsw0));
      const bf16x8 v1 = *(const bf16x8*)((const char*)Vs + (lq + 32) * 128 + (cb ^ rsw0));
      ot0 = mfma32(v0, pu.v, ot0);
      ot1 = mfma32(v1, pu.v, ot1);
    }
    __builtin_amdgcn_s_setprio(0);
    __syncthreads();                       // LDS reads done before next stage
  }
  // ---- epilogue: normalize, transpose via LDS, coalesced store
  const float inv = 1.0f / l;
#pragma unroll
  for (int r = 0; r < 16; ++r) {
    const int d0 = (r & 3) + 8 * (r >> 2) + 4 * hi5;
    osm[wave][lq][d0]      = f2bf(ot0[r] * inv);
    osm[wave][lq][32 + d0] = f2bf(ot1[r] * inv);
  }
  __syncthreads();
  const int col = (lane & 7) * 8;
#pragma unroll
  for (int pass = 0; pass < 4; ++pass) {
    const int row = pass * 8 + (lane >> 3);
    const bf16x8 vv = *(const bf16x8*)&osm[wave][row][col];
    const int qg = blockIdx.y * 128 + wave * 32 + row;
    *(bf16x8*)(att + (size_t)(b * 2048 + qg) * 768 + h * 64 + col) = vv;
  }
}

// ------------------------------------------------------------------ launch
extern "C" void kernel_launch(void* const* d_in, const int* in_sizes, int n_in,
                              void* d_out, int out_size, void* d_ws, size_t ws_size,
                              hipStream_t stream)
{
  const float* x     = (const float*)d_in[0];
  const float* tabx  = (const float*)d_in[1];
  const float* tab_g = (const float*)d_in[2];
  const float* tab_b = (const float*)d_in[3];
  const float* vid_g = (const float*)d_in[4];
  const float* vid_b = (const float*)d_in[5];
  const float* Wq    = (const float*)d_in[6];
  const float* Wk    = (const float*)d_in[7];
  const float* Wv    = (const float*)d_in[8];
  const float* q_g   = (const float*)d_in[9];
  const float* q_b   = (const float*)d_in[10];
  const float* k_g   = (const float*)d_in[11];
  const float* k_b   = (const float*)d_in[12];
  const float* Wo    = (const float*)d_in[13];
  const float* bo    = (const float*)d_in[14];

  char* ws = (char*)d_ws;
  const size_t O_WQT  = 0;
  const size_t O_WKVT = O_WQT  + (size_t)768 * 1024 * 2;   // 1536x1024 (Wk | Wv)
  const size_t O_WOT  = O_WKVT + (size_t)1536 * 1024 * 2;
  const size_t O_XN   = O_WOT  + (size_t)1024 * 768 * 2;
  const size_t O_KVN  = O_XN   + (size_t)8192 * 1024 * 2;
  const size_t O_QPRE = O_KVN  + (size_t)4096 * 1024 * 2;  // bf16
  const size_t O_KPRE = O_QPRE + (size_t)8192 * 768 * 2;   // bf16
  const size_t O_QB   = O_KPRE + (size_t)4096 * 768 * 2;
  const size_t O_KB   = O_QB   + (size_t)8192 * 768 * 2;
  const size_t O_VB   = O_KB   + (size_t)4096 * 768 * 2;
  const size_t O_VT   = O_VB   + (size_t)4096 * 768 * 2;
  const size_t O_ATT  = O_QPRE;   // alias: q_pre dead after its LN

  u16*   WqT   = (u16*)(ws + O_WQT);
  u16*   WkvT  = (u16*)(ws + O_WKVT);
  u16*   WoT   = (u16*)(ws + O_WOT);
  u16*   xn    = (u16*)(ws + O_XN);
  u16*   kvn   = (u16*)(ws + O_KVN);
  u16*   q_pre = (u16*)(ws + O_QPRE);
  u16*   k_pre = (u16*)(ws + O_KPRE);
  u16*   qb    = (u16*)(ws + O_QB);
  u16*   kb    = (u16*)(ws + O_KB);
  u16*   vb    = (u16*)(ws + O_VB);
  u16*   vT    = (u16*)(ws + O_VT);
  u16*   attb  = (u16*)(ws + O_ATT);

  transpose_w<<<dim3(32, 24), 256, 0, stream>>>(Wq, WqT, 1024, 768);
  transpose_w<<<dim3(32, 24), 256, 0, stream>>>(Wk, WkvT, 1024, 768);
  transpose_w<<<dim3(32, 24), 256, 0, stream>>>(Wv, WkvT + (size_t)768 * 1024, 1024, 768);
  transpose_w<<<dim3(24, 32), 256, 0, stream>>>(Wo, WoT, 768, 1024);
  ln_rows<<<4096, 256, 0, stream>>>(tabx, tab_g, tab_b, kvn, 1024, 1.0f);
  ln_rows<<<8192, 256, 0, stream>>>(x, vid_g, vid_b, xn, 1024, 1.0f);
  // merged k+v projection: N=1536, cols<768 -> k_pre (bf16), cols>=768 -> vb (bf16)
  gemm_bt<3><<<dim3(64, 12), 256, 0, stream>>>(kvn, WkvT, k_pre, vb, nullptr, 4096, 1536, 1024);
  ln_rows_bf<<<4096, 256, 0, stream>>>(k_pre, k_g, k_b, kb, 768, 1.0f);
  transpose_v<<<dim3(48, 16), 256, 0, stream>>>(vb, vT);
  gemm_bt<1><<<dim3(128, 6), 256, 0, stream>>>(xn, WqT, q_pre, nullptr, nullptr, 8192, 768, 1024);
  // q scale = (1/8) * log2(e): softmax computed in exp2 domain
  ln_rows_bf<<<8192, 256, 0, stream>>>(q_pre, q_g, q_b, qb, 768, 0.125f * 1.44269504089f);
  attn3<<<dim3(48, 16), 256, 0, stream>>>(qb, kb, vT, attb);
  gemm_bt<2><<<dim3(128, 8), 256, 0, stream>>>(attb, WoT, d_out, nullptr, bo, 8192, 1024, 768);
}

// Round 6
// 178.260 us; speedup vs baseline: 1.8539x; 1.0036x over previous
//
#include <hip/hip_runtime.h>

typedef unsigned short u16;
typedef float  f32x4   __attribute__((ext_vector_type(4)));
typedef float  f32x16  __attribute__((ext_vector_type(16)));
typedef __bf16 bf16x8  __attribute__((ext_vector_type(8)));
typedef u16    u16x4   __attribute__((ext_vector_type(4)));

#define DEV __device__ __forceinline__

DEV u16 f2bf(float f) {                 // round-to-nearest-even f32 -> bf16 bits
  union { float f; unsigned u; } x; x.f = f;
  unsigned r = x.u + 0x7fffu + ((x.u >> 16) & 1u);
  return (u16)(r >> 16);
}
DEV float bf2f(u16 b) { union { unsigned u; float f; } c; c.u = (unsigned)b << 16; return c.f; }

DEV unsigned cvtpk(float lo, float hi) { // packed bf16 pair: low16=lo, high16=hi (RNE)
  unsigned r;
  asm("v_cvt_pk_bf16_f32 %0, %1, %2" : "=v"(r) : "v"(lo), "v"(hi));
  return r;
}

DEV f32x4 mfma16(bf16x8 a, bf16x8 b, f32x4 c) {
  return __builtin_amdgcn_mfma_f32_16x16x32_bf16(a, b, c, 0, 0, 0);
}
DEV f32x16 mfma32(bf16x8 a, bf16x8 b, f32x16 c) {
  return __builtin_amdgcn_mfma_f32_32x32x16_bf16(a, b, c, 0, 0, 0);
}

DEV void gload16(const void* g, void* l) {   // async global->LDS, 16B/lane
  __builtin_amdgcn_global_load_lds(
      (__attribute__((address_space(1))) void*)g,
      (__attribute__((address_space(3))) void*)l, 16, 0, 0);
}

// ---------------------------------------------------------------- layernorm (fp32 in)
__global__ void ln_rows(const float* __restrict__ x, const float* __restrict__ g,
                        const float* __restrict__ bta, u16* __restrict__ y,
                        int C, float outscale)
{
  const int row = blockIdx.x;
  const int tid = threadIdx.x;
  const int n4 = C >> 2;
  const float* xr = x + (size_t)row * C;
  f32x4 v = {0.f, 0.f, 0.f, 0.f};
  if (tid < n4) v = *(const f32x4*)(xr + 4 * tid);
  float s1 = v[0] + v[1] + v[2] + v[3];
  float s2 = v[0]*v[0] + v[1]*v[1] + v[2]*v[2] + v[3]*v[3];
#pragma unroll
  for (int o = 32; o > 0; o >>= 1) {
    s1 += __shfl_xor(s1, o, 64);
    s2 += __shfl_xor(s2, o, 64);
  }
  __shared__ float red[8];
  const int lane = tid & 63, wv = tid >> 6;
  if (lane == 0) { red[wv] = s1; red[4 + wv] = s2; }
  __syncthreads();
  s1 = red[0] + red[1] + red[2] + red[3];
  s2 = red[4] + red[5] + red[6] + red[7];
  const float mu = s1 / C;
  const float rs = rsqrtf(s2 / C - mu * mu + 1e-5f);
  if (tid < n4) {
    f32x4 gg = *(const f32x4*)(g + 4 * tid);
    f32x4 bb = *(const f32x4*)(bta + 4 * tid);
    u16x4 o4;
#pragma unroll
    for (int j = 0; j < 4; ++j)
      o4[j] = f2bf(((v[j] - mu) * rs * gg[j] + bb[j]) * outscale);
    *(u16x4*)(y + (size_t)row * C + 4 * tid) = o4;
  }
}

// ---------------------------------------------------------------- layernorm (bf16 in)
__global__ void ln_rows_bf(const u16* __restrict__ x, const float* __restrict__ g,
                           const float* __restrict__ bta, u16* __restrict__ y,
                           int C, float outscale)
{
  const int row = blockIdx.x;
  const int tid = threadIdx.x;
  const int n4 = C >> 2;
  const u16* xr = x + (size_t)row * C;
  f32x4 v = {0.f, 0.f, 0.f, 0.f};
  if (tid < n4) {
    const u16x4 raw = *(const u16x4*)(xr + 4 * tid);
#pragma unroll
    for (int j = 0; j < 4; ++j) v[j] = bf2f(raw[j]);
  }
  float s1 = v[0] + v[1] + v[2] + v[3];
  float s2 = v[0]*v[0] + v[1]*v[1] + v[2]*v[2] + v[3]*v[3];
#pragma unroll
  for (int o = 32; o > 0; o >>= 1) {
    s1 += __shfl_xor(s1, o, 64);
    s2 += __shfl_xor(s2, o, 64);
  }
  __shared__ float red[8];
  const int lane = tid & 63, wv = tid >> 6;
  if (lane == 0) { red[wv] = s1; red[4 + wv] = s2; }
  __syncthreads();
  s1 = red[0] + red[1] + red[2] + red[3];
  s2 = red[4] + red[5] + red[6] + red[7];
  const float mu = s1 / C;
  const float rs = rsqrtf(s2 / C - mu * mu + 1e-5f);
  if (tid < n4) {
    f32x4 gg = *(const f32x4*)(g + 4 * tid);
    f32x4 bb = *(const f32x4*)(bta + 4 * tid);
    u16x4 o4;
#pragma unroll
    for (int j = 0; j < 4; ++j)
      o4[j] = f2bf(((v[j] - mu) * rs * gg[j] + bb[j]) * outscale);
    *(u16x4*)(y + (size_t)row * C + 4 * tid) = o4;
  }
}

// ------------------------------------------------------- weight fp32 -> bf16^T
__global__ void transpose_w(const float* __restrict__ w, u16* __restrict__ wt,
                            int K, int N)
{
  __shared__ float t[32][33];
  const int k0 = blockIdx.x * 32, n0 = blockIdx.y * 32;
  const int tx = threadIdx.x & 31, ty = threadIdx.x >> 5;
#pragma unroll
  for (int i = ty; i < 32; i += 8)
    t[i][tx] = w[(size_t)(k0 + i) * N + n0 + tx];
  __syncthreads();
#pragma unroll
  for (int i = ty; i < 32; i += 8)
    wt[(size_t)(n0 + i) * K + k0 + tx] = f2bf(t[tx][i]);
}

// ------------------------------------------------------------- V transpose
__global__ void transpose_v(const u16* __restrict__ v, u16* __restrict__ vt)
{
  __shared__ u16 t[64][65];
  const int bh = blockIdx.x, b = bh / 12, h = bh - b * 12;
  const int j0 = blockIdx.y * 64;
  const int tx = threadIdx.x & 63, ty = threadIdx.x >> 6;
#pragma unroll
  for (int i = ty; i < 64; i += 4)
    t[i][tx] = v[(size_t)(b * 1024 + j0 + i) * 768 + h * 64 + tx];
  __syncthreads();
#pragma unroll
  for (int i = ty; i < 64; i += 4)
    vt[((size_t)bh * 64 + i) * 1024 + j0 + tx] = t[tx][i];
}

// ------------------------------------------------------------------- GEMM
// C[M][N] = A[M][K] * Bt[N][K]^T; BM=64, BN=128, BK=64, 4 waves, wave 32x64.
// 2-phase double-buffered pipeline: STAGE(t+1) issued before compute(t); one
// vmcnt(0)+barrier per K-tile (via __syncthreads) drains stage + read reuse.
// MODE 1: bf16 store; MODE 2: fp32+bias; MODE 3: split k/v epilogue
//   (cols < 768 -> bf16 Cp pitch 768; cols >= 768 -> bf16 Cp2 pitch 768).
template<int MODE>
__global__ __launch_bounds__(256)
void gemm_bt(const u16* __restrict__ A, const u16* __restrict__ Bt,
             void* __restrict__ Cp, void* __restrict__ Cp2,
             const float* __restrict__ bias, int M, int N, int K)
{
  __shared__ __align__(16) u16 As[2][64 * 64];    // 2 x 8 KB
  __shared__ __align__(16) u16 Bs[2][128 * 64];   // 2 x 16 KB
  const int tid  = threadIdx.x;
  const int lane = tid & 63;
  const int wave = tid >> 6;
  const int bm = blockIdx.x * 64;
  const int bn = blockIdx.y * 128;
  const int wm = (wave >> 1) * 32;
  const int wn = (wave & 1) * 64;
  const int fr = lane & 15;
  const int fk = (lane >> 4) * 8;

  f32x4 acc[2][4] = {};

  const char* gA0 = (const char*)(A  + (size_t)bm * K);
  const char* gB0 = (const char*)(Bt + (size_t)bn * K);
  const size_t rowpitch = (size_t)K * 2;
  const int nt = K >> 6;

  auto stage = [&](int buf, int k0) {
#pragma unroll
    for (int c = 0; c < 2; ++c) {
      const int off = tid * 16 + c * 4096;
      gload16(gA0 + (size_t)(off >> 7) * rowpitch + 2 * k0 + (off & 127),
              (char*)&As[buf][0] + wave * 1024 + c * 4096);
    }
#pragma unroll
    for (int c = 0; c < 4; ++c) {
      const int off = tid * 16 + c * 4096;
      gload16(gB0 + (size_t)(off >> 7) * rowpitch + 2 * k0 + (off & 127),
              (char*)&Bs[buf][0] + wave * 1024 + c * 4096);
    }
  };

  stage(0, 0);
  __syncthreads();                       // buf0 staged (vmcnt(0) + barrier)
  int cur = 0;
  for (int t = 0; t < nt; ++t) {
    if (t + 1 < nt) stage(cur ^ 1, (t + 1) * 64);   // prefetch next tile FIRST
    bf16x8 af[2][2], bg[4][2];
#pragma unroll
    for (int m = 0; m < 2; ++m)
#pragma unroll
      for (int kk = 0; kk < 2; ++kk)
        af[m][kk] = *(const bf16x8*)&As[cur][(wm + m * 16 + fr) * 64 + kk * 32 + fk];
#pragma unroll
    for (int n = 0; n < 4; ++n)
#pragma unroll
      for (int kk = 0; kk < 2; ++kk)
        bg[n][kk] = *(const bf16x8*)&Bs[cur][(wn + n * 16 + fr) * 64 + kk * 32 + fk];
#pragma unroll
    for (int kk = 0; kk < 2; ++kk)
#pragma unroll
      for (int m = 0; m < 2; ++m)
#pragma unroll
        for (int n = 0; n < 4; ++n)
          acc[m][n] = mfma16(af[m][kk], bg[n][kk], acc[m][n]);
    if (t + 1 < nt) __syncthreads();     // next tile ready; reads of cur done
    cur ^= 1;
  }

  const int orow0 = bm + wm + 4 * (lane >> 4);
  const int ocol0 = bn + wn + fr;
#pragma unroll
  for (int m = 0; m < 2; ++m)
#pragma unroll
    for (int n = 0; n < 4; ++n)
#pragma unroll
      for (int r = 0; r < 4; ++r) {
        const int row = orow0 + m * 16 + r;
        const int col = ocol0 + n * 16;
        float v = acc[m][n][r];
        if (MODE == 2) v += bias[col];
        if (MODE == 3) {
          if (bn < 768) ((u16*)Cp)[(size_t)row * 768 + col] = f2bf(v);
          else          ((u16*)Cp2)[(size_t)row * 768 + (col - 768)] = f2bf(v);
        } else if (MODE == 1) {
          ((u16*)Cp)[(size_t)row * N + col] = f2bf(v);
        } else {
          ((float*)Cp)[(size_t)row * N + col] = v;
        }
      }
}

// --------------------------------------------------------------- attention v4
// Swapped QK^T on 32x32x16 MFMA; lane-local softmax (q = lane&31), exp2-domain;
// P -> PV B-fragment via cvt_pk + permlane32_swap.
// K/V tiles staged in LDS per block (coalesced global_load_lds, shared by all
// 4 waves) with T2-style XOR swizzle (rule #21). Max-reduce via v_max3 fusion.
__global__ __launch_bounds__(256, 3)
void attn3(const u16* __restrict__ q, const u16* __restrict__ k,
           const u16* __restrict__ vT, u16* __restrict__ att)
{
  __shared__ __align__(16) u16 Ks[64 * 64];     // 8 KB: K tile [j][d]
  __shared__ __align__(16) u16 Vs[64 * 64];     // 8 KB: V tile [d][j]
  __shared__ __align__(16) u16 osm[4][32][72];  // epilogue transpose

  const int bh = blockIdx.x;
  const int b = bh / 12, h = bh - b * 12;
  const int tid = threadIdx.x, lane = tid & 63, wave = tid >> 6;
  const int lq  = lane & 31;
  const int hi5 = lane >> 5;
  const int qrow = blockIdx.y * 128 + wave * 32 + lq;

  const u16* qp = q + (size_t)(b * 2048 + qrow) * 768 + h * 64 + hi5 * 8;
  bf16x8 qf[4];
#pragma unroll
  for (int ds = 0; ds < 4; ++ds) qf[ds] = *(const bf16x8*)(qp + ds * 16);

  f32x16 ot0 = {}, ot1 = {};
  float m = -1e30f, l = 0.f;

  // global byte bases
  const char* kg = (const char*)k + (size_t)(b * 1024) * 1536 + h * 128;
  const char* vg = (const char*)vT + (size_t)bh * 64 * 2048;

  // swizzled read offsets (within a 128B row: byte ^= (row&7)<<4)
  const int rsw0 = (lq & 7) << 4;

  for (int j0 = 0; j0 < 1024; j0 += 64) {
    // ---- stage K[64][64] and V[64][64] (8KB each), source pre-swizzled
#pragma unroll
    for (int c = 0; c < 2; ++c) {
      const int o   = tid * 16 + c * 4096;
      const int row = o >> 7;
      const int scol = (o & 127) ^ ((row & 7) << 4);
      gload16(kg + (size_t)(j0 + row) * 1536 + scol,
              (char*)Ks + wave * 1024 + c * 4096);
      gload16(vg + (size_t)row * 2048 + j0 * 2 + scol,
              (char*)Vs + wave * 1024 + c * 4096);
    }
    __syncthreads();                       // drains vmcnt -> tiles ready
    // ---- S^T = K * Q^T
    f32x16 st0 = {}, st1 = {};
    __builtin_amdgcn_s_setprio(1);
#pragma unroll
    for (int ds = 0; ds < 4; ++ds) {
      const int cb = ds * 32 + hi5 * 16;
      const bf16x8 k0 = *(const bf16x8*)((const char*)Ks + lq * 128 + (cb ^ rsw0));
      const bf16x8 k1 = *(const bf16x8*)((const char*)Ks + (lq + 32) * 128 + (cb ^ rsw0));
      st0 = mfma32(k0, qf[ds], st0);
      st1 = mfma32(k1, qf[ds], st1);
    }
    __builtin_amdgcn_s_setprio(0);
    // ---- online softmax (exp2 domain); max chains shaped for v_max3 fusion
    float ta0 = fmaxf(st0[0], st1[0]), ta1 = fmaxf(st0[1], st1[1]);
    float ta2 = fmaxf(st0[2], st1[2]), ta3 = fmaxf(st0[3], st1[3]);
#pragma unroll
    for (int r = 4; r < 16; r += 4) {
      ta0 = fmaxf(fmaxf(st0[r],     st1[r]),     ta0);
      ta1 = fmaxf(fmaxf(st0[r + 1], st1[r + 1]), ta1);
      ta2 = fmaxf(fmaxf(st0[r + 2], st1[r + 2]), ta2);
      ta3 = fmaxf(fmaxf(st0[r + 3], st1[r + 3]), ta3);
    }
    float tmax = fmaxf(fmaxf(fmaxf(ta0, ta1), ta2), ta3);
    tmax = fmaxf(tmax, __shfl_xor(tmax, 32, 64));
    if (!__all(tmax - m <= 11.5416f)) {          // defer-max, THR = 8*log2e
      const float mn = fmaxf(m, tmax);
      const float sc = exp2f(m - mn);
      l *= sc;
#pragma unroll
      for (int r = 0; r < 16; ++r) { ot0[r] *= sc; ot1[r] *= sc; }
      m = mn;
    }
    float sa0 = 0.f, sa1 = 0.f, sa2 = 0.f, sa3 = 0.f;
#pragma unroll
    for (int r = 0; r < 16; r += 4) {
      float p0 = exp2f(st0[r]     - m); st0[r]     = p0; sa0 += p0;
      float p1 = exp2f(st0[r + 1] - m); st0[r + 1] = p1; sa1 += p1;
      float p2 = exp2f(st0[r + 2] - m); st0[r + 2] = p2; sa2 += p2;
      float p3 = exp2f(st0[r + 3] - m); st0[r + 3] = p3; sa3 += p3;
    }
#pragma unroll
    for (int r = 0; r < 16; r += 4) {
      float p0 = exp2f(st1[r]     - m); st1[r]     = p0; sa0 += p0;
      float p1 = exp2f(st1[r + 1] - m); st1[r + 1] = p1; sa1 += p1;
      float p2 = exp2f(st1[r + 2] - m); st1[r + 2] = p2; sa2 += p2;
      float p3 = exp2f(st1[r + 3] - m); st1[r + 3] = p3; sa3 += p3;
    }
    float ts = (sa0 + sa1) + (sa2 + sa3);
    ts += __shfl_xor(ts, 32, 64);
    l += ts;
    // ---- PV
    __builtin_amdgcn_s_setprio(1);
#pragma unroll
    for (int s4 = 0; s4 < 4; ++s4) {
      const int u = (s4 & 1) * 8;
      float a0, a1, a2, a3, b0, b1, b2, b3;
      if (s4 < 2) {
        a0 = st0[u]; a1 = st0[u + 1]; a2 = st0[u + 2]; a3 = st0[u + 3];
        b0 = st0[u + 4]; b1 = st0[u + 5]; b2 = st0[u + 6]; b3 = st0[u + 7];
      } else {
        a0 = st1[u]; a1 = st1[u + 1]; a2 = st1[u + 2]; a3 = st1[u + 3];
        b0 = st1[u + 4]; b1 = st1[u + 5]; b2 = st1[u + 6]; b3 = st1[u + 7];
      }
      const unsigned L0 = cvtpk(a0, a1), L1 = cvtpk(a2, a3);
      const unsigned H0 = cvtpk(b0, b1), H1 = cvtpk(b2, b3);
      const auto w02 = __builtin_amdgcn_permlane32_swap(L0, H0, false, false);
      const auto w13 = __builtin_amdgcn_permlane32_swap(L1, H1, false, false);
      union BU { unsigned w[4]; bf16x8 v; } pu;
      pu.w[0] = w02[0]; pu.w[1] = w13[0]; pu.w[2] = w02[1]; pu.w[3] = w13[1];
      const int cb = s4 * 32 + hi5 * 16;
      const bf16x8 v0 = *(const bf16x8*)((const char*)Vs + lq * 128 + (cb ^ rsw0));
      const bf16x8 v1 = *(const bf16x8*)((const char*)Vs + (lq + 32) * 128 + (cb ^ rsw0));
      ot0 = mfma32(v0, pu.v, ot0);
      ot1 = mfma32(v1, pu.v, ot1);
    }
    __builtin_amdgcn_s_setprio(0);
    __syncthreads();                       // LDS reads done before next stage
  }
  // ---- epilogue: normalize, transpose via LDS, coalesced store
  const float inv = 1.0f / l;
#pragma unroll
  for (int r = 0; r < 16; ++r) {
    const int d0 = (r & 3) + 8 * (r >> 2) + 4 * hi5;
    osm[wave][lq][d0]      = f2bf(ot0[r] * inv);
    osm[wave][lq][32 + d0] = f2bf(ot1[r] * inv);
  }
  __syncthreads();
  const int col = (lane & 7) * 8;
#pragma unroll
  for (int pass = 0; pass < 4; ++pass) {
    const int row = pass * 8 + (lane >> 3);
    const bf16x8 vv = *(const bf16x8*)&osm[wave][row][col];
    const int qg = blockIdx.y * 128 + wave * 32 + row;
    *(bf16x8*)(att + (size_t)(b * 2048 + qg) * 768 + h * 64 + col) = vv;
  }
}

// ------------------------------------------------------------------ launch
extern "C" void kernel_launch(void* const* d_in, const int* in_sizes, int n_in,
                              void* d_out, int out_size, void* d_ws, size_t ws_size,
                              hipStream_t stream)
{
  const float* x     = (const float*)d_in[0];
  const float* tabx  = (const float*)d_in[1];
  const float* tab_g = (const float*)d_in[2];
  const float* tab_b = (const float*)d_in[3];
  const float* vid_g = (const float*)d_in[4];
  const float* vid_b = (const float*)d_in[5];
  const float* Wq    = (const float*)d_in[6];
  const float* Wk    = (const float*)d_in[7];
  const float* Wv    = (const float*)d_in[8];
  const float* q_g   = (const float*)d_in[9];
  const float* q_b   = (const float*)d_in[10];
  const float* k_g   = (const float*)d_in[11];
  const float* k_b   = (const float*)d_in[12];
  const float* Wo    = (const float*)d_in[13];
  const float* bo    = (const float*)d_in[14];

  char* ws = (char*)d_ws;
  const size_t O_WQT  = 0;
  const size_t O_WKVT = O_WQT  + (size_t)768 * 1024 * 2;   // 1536x1024 (Wk | Wv)
  const size_t O_WOT  = O_WKVT + (size_t)1536 * 1024 * 2;
  const size_t O_XN   = O_WOT  + (size_t)1024 * 768 * 2;
  const size_t O_KVN  = O_XN   + (size_t)8192 * 1024 * 2;
  const size_t O_QPRE = O_KVN  + (size_t)4096 * 1024 * 2;  // bf16
  const size_t O_KPRE = O_QPRE + (size_t)8192 * 768 * 2;   // bf16
  const size_t O_QB   = O_KPRE + (size_t)4096 * 768 * 2;
  const size_t O_KB   = O_QB   + (size_t)8192 * 768 * 2;
  const size_t O_VB   = O_KB   + (size_t)4096 * 768 * 2;
  const size_t O_VT   = O_VB   + (size_t)4096 * 768 * 2;
  const size_t O_ATT  = O_QPRE;   // alias: q_pre dead after its LN

  u16*   WqT   = (u16*)(ws + O_WQT);
  u16*   WkvT  = (u16*)(ws + O_WKVT);
  u16*   WoT   = (u16*)(ws + O_WOT);
  u16*   xn    = (u16*)(ws + O_XN);
  u16*   kvn   = (u16*)(ws + O_KVN);
  u16*   q_pre = (u16*)(ws + O_QPRE);
  u16*   k_pre = (u16*)(ws + O_KPRE);
  u16*   qb    = (u16*)(ws + O_QB);
  u16*   kb    = (u16*)(ws + O_KB);
  u16*   vb    = (u16*)(ws + O_VB);
  u16*   vT    = (u16*)(ws + O_VT);
  u16*   attb  = (u16*)(ws + O_ATT);

  transpose_w<<<dim3(32, 24), 256, 0, stream>>>(Wq, WqT, 1024, 768);
  transpose_w<<<dim3(32, 24), 256, 0, stream>>>(Wk, WkvT, 1024, 768);
  transpose_w<<<dim3(32, 24), 256, 0, stream>>>(Wv, WkvT + (size_t)768 * 1024, 1024, 768);
  transpose_w<<<dim3(24, 32), 256, 0, stream>>>(Wo, WoT, 768, 1024);
  ln_rows<<<4096, 256, 0, stream>>>(tabx, tab_g, tab_b, kvn, 1024, 1.0f);
  ln_rows<<<8192, 256, 0, stream>>>(x, vid_g, vid_b, xn, 1024, 1.0f);
  // merged k+v projection: N=1536, cols<768 -> k_pre (bf16), cols>=768 -> vb (bf16)
  gemm_bt<3><<<dim3(64, 12), 256, 0, stream>>>(kvn, WkvT, k_pre, vb, nullptr, 4096, 1536, 1024);
  ln_rows_bf<<<4096, 256, 0, stream>>>(k_pre, k_g, k_b, kb, 768, 1.0f);
  transpose_v<<<dim3(48, 16), 256, 0, stream>>>(vb, vT);
  gemm_bt<1><<<dim3(128, 6), 256, 0, stream>>>(xn, WqT, q_pre, nullptr, nullptr, 8192, 768, 1024);
  // q scale = (1/8) * log2(e): softmax computed in exp2 domain
  ln_rows_bf<<<8192, 256, 0, stream>>>(q_pre, q_g, q_b, qb, 768, 0.125f * 1.44269504089f);
  attn3<<<dim3(48, 16), 256, 0, stream>>>(qb, kb, vT, attb);
  gemm_bt<2><<<dim3(128, 8), 256, 0, stream>>>(attb, WoT, d_out, nullptr, bo, 8192, 1024, 768);
}

// Round 7
// 156.889 us; speedup vs baseline: 2.1064x; 1.1362x over previous
//
#include <hip/hip_runtime.h>

typedef unsigned short u16;
typedef float  f32x4   __attribute__((ext_vector_type(4)));
typedef float  f32x16  __attribute__((ext_vector_type(16)));
typedef __bf16 bf16x8  __attribute__((ext_vector_type(8)));
typedef u16    u16x4   __attribute__((ext_vector_type(4)));

#define DEV __device__ __forceinline__

DEV u16 f2bf(float f) {                 // round-to-nearest-even f32 -> bf16 bits
  union { float f; unsigned u; } x; x.f = f;
  unsigned r = x.u + 0x7fffu + ((x.u >> 16) & 1u);
  return (u16)(r >> 16);
}
DEV float bf2f(u16 b) { union { unsigned u; float f; } c; c.u = (unsigned)b << 16; return c.f; }

DEV unsigned cvtpk(float lo, float hi) { // packed bf16 pair: low16=lo, high16=hi (RNE)
  unsigned r;
  asm("v_cvt_pk_bf16_f32 %0, %1, %2" : "=v"(r) : "v"(lo), "v"(hi));
  return r;
}

DEV f32x4 mfma16(bf16x8 a, bf16x8 b, f32x4 c) {
  return __builtin_amdgcn_mfma_f32_16x16x32_bf16(a, b, c, 0, 0, 0);
}
DEV f32x16 mfma32(bf16x8 a, bf16x8 b, f32x16 c) {
  return __builtin_amdgcn_mfma_f32_32x32x16_bf16(a, b, c, 0, 0, 0);
}

DEV void gload16(const void* g, void* l) {   // async global->LDS, 16B/lane
  __builtin_amdgcn_global_load_lds(
      (__attribute__((address_space(1))) void*)g,
      (__attribute__((address_space(3))) void*)l, 16, 0, 0);
}

// ---------------------------------------------------------- LN row body (shared)
template<typename LOADER>
DEV void ln_body(LOADER load, const float* __restrict__ g, const float* __restrict__ bta,
                 u16* __restrict__ yrow, int C, float outscale, float* red)
{
  const int tid = threadIdx.x;
  const int n4 = C >> 2;
  f32x4 v = {0.f, 0.f, 0.f, 0.f};
  if (tid < n4) v = load(tid);
  float s1 = v[0] + v[1] + v[2] + v[3];
  float s2 = v[0]*v[0] + v[1]*v[1] + v[2]*v[2] + v[3]*v[3];
#pragma unroll
  for (int o = 32; o > 0; o >>= 1) {
    s1 += __shfl_xor(s1, o, 64);
    s2 += __shfl_xor(s2, o, 64);
  }
  const int lane = tid & 63, wv = tid >> 6;
  if (lane == 0) { red[wv] = s1; red[4 + wv] = s2; }
  __syncthreads();
  s1 = red[0] + red[1] + red[2] + red[3];
  s2 = red[4] + red[5] + red[6] + red[7];
  const float mu = s1 / C;
  const float rs = rsqrtf(s2 / C - mu * mu + 1e-5f);
  if (tid < n4) {
    f32x4 gg = *(const f32x4*)(g + 4 * tid);
    f32x4 bb = *(const f32x4*)(bta + 4 * tid);
    u16x4 o4;
#pragma unroll
    for (int j = 0; j < 4; ++j)
      o4[j] = f2bf(((v[j] - mu) * rs * gg[j] + bb[j]) * outscale);
    *(u16x4*)(yrow + 4 * tid) = o4;
  }
}

// ---------------------------------------------------------------------- prep
// bid [0,3072):   Wq/Wk/Wv transpose (1024x768 f32 -> 768x1024 bf16)
// bid [3072,3840): Wo transpose (768x1024 -> 1024x768)
// bid [3840,16128): input layernorms (tabx 4096 rows, x 8192 rows; C=1024)
__global__ __launch_bounds__(256)
void prep(const float* __restrict__ Wq, const float* __restrict__ Wk,
          const float* __restrict__ Wv, const float* __restrict__ Wo,
          u16* __restrict__ WqT, u16* __restrict__ WkvT, u16* __restrict__ WoT,
          const float* __restrict__ tabx, const float* __restrict__ tab_g,
          const float* __restrict__ tab_b,
          const float* __restrict__ x, const float* __restrict__ vid_g,
          const float* __restrict__ vid_b,
          u16* __restrict__ kvn, u16* __restrict__ xn)
{
  __shared__ float t[32][33];
  __shared__ float red[8];
  const int bid = blockIdx.x;
  const int tid = threadIdx.x;
  if (bid < 3840) {                  // ---- weight transposes
    const float* src; u16* dst; int K, N, k0, n0;
    if (bid < 3072) {
      const int w = bid / 768, r = bid % 768;
      src = (w == 0) ? Wq : (w == 1) ? Wk : Wv;
      dst = (w == 0) ? WqT : (w == 1) ? WkvT : WkvT + (size_t)768 * 1024;
      K = 1024; N = 768; k0 = (r % 32) * 32; n0 = (r / 32) * 32;
    } else {
      const int r = bid - 3072;
      src = Wo; dst = WoT;
      K = 768; N = 1024; k0 = (r % 24) * 32; n0 = (r / 24) * 32;
    }
    const int tx = tid & 31, ty = tid >> 5;
#pragma unroll
    for (int i = ty; i < 32; i += 8)
      t[i][tx] = src[(size_t)(k0 + i) * N + n0 + tx];
    __syncthreads();
#pragma unroll
    for (int i = ty; i < 32; i += 8)
      dst[(size_t)(n0 + i) * K + k0 + tx] = f2bf(t[tx][i]);
  } else {                           // ---- input LN (C=1024)
    const int r = bid - 3840;
    const float* xr; const float *g, *bb; u16* y;
    if (r < 4096) { xr = tabx + (size_t)r * 1024; g = tab_g; bb = tab_b;
                    y = kvn + (size_t)r * 1024; }
    else { const int rr = r - 4096; xr = x + (size_t)rr * 1024; g = vid_g;
           bb = vid_b; y = xn + (size_t)rr * 1024; }
    ln_body([&](int i) { return *(const f32x4*)(xr + 4 * i); }, g, bb, y, 1024, 1.0f, red);
  }
}

// ------------------------------------------------------------------ gemm_qkv
// bid [0,768):   kv GEMM: kvn[4096][1024] x WkvT[1536][1024]^T, split epilogue
// bid [768,1536): q GEMM: xn[8192][1024] x WqT[768][1024]^T -> q_pre bf16
// BM=64, BN=128, BK=64, 4 waves, 2-phase double-buffered.
__global__ __launch_bounds__(256)
void gemm_qkv(const u16* __restrict__ xn, const u16* __restrict__ kvn,
              const u16* __restrict__ WqT, const u16* __restrict__ WkvT,
              u16* __restrict__ q_pre, u16* __restrict__ k_pre, u16* __restrict__ vb)
{
  __shared__ __align__(16) u16 As[2][64 * 64];
  __shared__ __align__(16) u16 Bs[2][128 * 64];
  const int bid = blockIdx.x;
  const int tid  = threadIdx.x;
  const int lane = tid & 63;
  const int wave = tid >> 6;
  const bool isq = bid >= 768;
  const u16* A; const u16* Bt; int bm, bn;
  if (!isq) { A = kvn;  Bt = WkvT; bm = (bid & 63) * 64;  bn = (bid >> 6) * 128; }
  else { const int r = bid - 768; A = xn; Bt = WqT; bm = (r & 127) * 64; bn = (r >> 7) * 128; }
  const int wm = (wave >> 1) * 32;
  const int wn = (wave & 1) * 64;
  const int fr = lane & 15;
  const int fk = (lane >> 4) * 8;

  f32x4 acc[2][4] = {};
  const char* gA0 = (const char*)(A  + (size_t)bm * 1024);
  const char* gB0 = (const char*)(Bt + (size_t)bn * 1024);
  const size_t rowpitch = 2048;

  auto stage = [&](int buf, int k0) {
#pragma unroll
    for (int c = 0; c < 2; ++c) {
      const int off = tid * 16 + c * 4096;
      gload16(gA0 + (size_t)(off >> 7) * rowpitch + 2 * k0 + (off & 127),
              (char*)&As[buf][0] + wave * 1024 + c * 4096);
    }
#pragma unroll
    for (int c = 0; c < 4; ++c) {
      const int off = tid * 16 + c * 4096;
      gload16(gB0 + (size_t)(off >> 7) * rowpitch + 2 * k0 + (off & 127),
              (char*)&Bs[buf][0] + wave * 1024 + c * 4096);
    }
  };

  stage(0, 0);
  __syncthreads();
  int cur = 0;
  for (int t = 0; t < 16; ++t) {
    if (t + 1 < 16) stage(cur ^ 1, (t + 1) * 64);
    bf16x8 af[2][2], bg[4][2];
#pragma unroll
    for (int m = 0; m < 2; ++m)
#pragma unroll
      for (int kk = 0; kk < 2; ++kk)
        af[m][kk] = *(const bf16x8*)&As[cur][(wm + m * 16 + fr) * 64 + kk * 32 + fk];
#pragma unroll
    for (int n = 0; n < 4; ++n)
#pragma unroll
      for (int kk = 0; kk < 2; ++kk)
        bg[n][kk] = *(const bf16x8*)&Bs[cur][(wn + n * 16 + fr) * 64 + kk * 32 + fk];
#pragma unroll
    for (int kk = 0; kk < 2; ++kk)
#pragma unroll
      for (int m = 0; m < 2; ++m)
#pragma unroll
        for (int n = 0; n < 4; ++n)
          acc[m][n] = mfma16(af[m][kk], bg[n][kk], acc[m][n]);
    if (t + 1 < 16) __syncthreads();
    cur ^= 1;
  }

  const int orow0 = bm + wm + 4 * (lane >> 4);
  const int ocol0 = bn + wn + fr;
#pragma unroll
  for (int m = 0; m < 2; ++m)
#pragma unroll
    for (int n = 0; n < 4; ++n)
#pragma unroll
      for (int r = 0; r < 4; ++r) {
        const int row = orow0 + m * 16 + r;
        const int col = ocol0 + n * 16;
        const u16 v = f2bf(acc[m][n][r]);
        if (isq) q_pre[(size_t)row * 768 + col] = v;
        else if (bn < 768) k_pre[(size_t)row * 768 + col] = v;
        else               vb[(size_t)row * 768 + (col - 768)] = v;
      }
}

// --------------------------------------------------------------------- ln_tv
// bid [0,4096):    LN k_pre -> kb (C=768, scale 1)
// bid [4096,12288): LN q_pre -> qb (C=768, scale 0.125*log2e)
// bid [12288,13056): transpose_v jobs
__global__ __launch_bounds__(256)
void ln_tv(const u16* __restrict__ k_pre, const float* __restrict__ k_g,
           const float* __restrict__ k_b, u16* __restrict__ kb,
           const u16* __restrict__ q_pre, const float* __restrict__ q_g,
           const float* __restrict__ q_b, u16* __restrict__ qb,
           const u16* __restrict__ vb, u16* __restrict__ vT)
{
  __shared__ u16 t[64][65];
  __shared__ float red[8];
  const int bid = blockIdx.x;
  const int tid = threadIdx.x;
  if (bid < 12288) {
    const bool isk = bid < 4096;
    const int row = isk ? bid : bid - 4096;
    const u16* xr = (isk ? k_pre : q_pre) + (size_t)row * 768;
    u16* y = (isk ? kb : qb) + (size_t)row * 768;
    const float sc = isk ? 1.0f : 0.125f * 1.44269504089f;
    ln_body([&](int i) {
      const u16x4 raw = *(const u16x4*)(xr + 4 * i);
      f32x4 v; 
#pragma unroll
      for (int j = 0; j < 4; ++j) v[j] = bf2f(raw[j]);
      return v;
    }, isk ? k_g : q_g, isk ? k_b : q_b, y, 768, sc, red);
  } else {
    const int r2 = bid - 12288;
    const int bh = r2 % 48, b = bh / 12, h = bh - b * 12;
    const int j0 = (r2 / 48) * 64;
    const int tx = tid & 63, ty = tid >> 6;
#pragma unroll
    for (int i = ty; i < 64; i += 4)
      t[i][tx] = vb[(size_t)(b * 1024 + j0 + i) * 768 + h * 64 + tx];
    __syncthreads();
#pragma unroll
    for (int i = ty; i < 64; i += 4)
      vT[((size_t)bh * 64 + i) * 1024 + j0 + tx] = t[tx][i];
  }
}

// --------------------------------------------------------------- attention v5
// Swapped QK^T on 32x32x16 MFMA; lane-local softmax; cvt_pk + permlane32_swap;
// K/V LDS staging with XOR swizzle, now DOUBLE-BUFFERED with a single
// __syncthreads per j-tile: stage(next) -> compute(cur) -> sync.
__global__ __launch_bounds__(256, 3)
void attn4(const u16* __restrict__ q, const u16* __restrict__ k,
           const u16* __restrict__ vT, u16* __restrict__ att)
{
  __shared__ __align__(16) u16 Ks[2][64 * 64];
  __shared__ __align__(16) u16 Vs[2][64 * 64];
  __shared__ __align__(16) u16 osm[4][32][72];

  const int bh = blockIdx.x;
  const int b = bh / 12, h = bh - b * 12;
  const int tid = threadIdx.x, lane = tid & 63, wave = tid >> 6;
  const int lq  = lane & 31;
  const int hi5 = lane >> 5;
  const int qrow = blockIdx.y * 128 + wave * 32 + lq;

  const u16* qp = q + (size_t)(b * 2048 + qrow) * 768 + h * 64 + hi5 * 8;
  bf16x8 qf[4];
#pragma unroll
  for (int ds = 0; ds < 4; ++ds) qf[ds] = *(const bf16x8*)(qp + ds * 16);

  f32x16 ot0 = {}, ot1 = {};
  float m = -1e30f, l = 0.f;

  const char* kg = (const char*)k + (size_t)(b * 1024) * 1536 + h * 128;
  const char* vg = (const char*)vT + (size_t)bh * 64 * 2048;
  const int rsw0 = (lq & 7) << 4;

  auto stage = [&](int buf, int j0) {
#pragma unroll
    for (int c = 0; c < 2; ++c) {
      const int o   = tid * 16 + c * 4096;
      const int row = o >> 7;
      const int scol = (o & 127) ^ ((row & 7) << 4);
      gload16(kg + (size_t)(j0 + row) * 1536 + scol,
              (char*)&Ks[buf][0] + wave * 1024 + c * 4096);
      gload16(vg + (size_t)row * 2048 + j0 * 2 + scol,
              (char*)&Vs[buf][0] + wave * 1024 + c * 4096);
    }
  };

  stage(0, 0);
  __syncthreads();
  int cur = 0;
  for (int t = 0; t < 16; ++t) {
    const int j0 = t * 64;
    if (t + 1 < 16) stage(cur ^ 1, j0 + 64);
    // ---- S^T = K * Q^T
    f32x16 st0 = {}, st1 = {};
    __builtin_amdgcn_s_setprio(1);
#pragma unroll
    for (int ds = 0; ds < 4; ++ds) {
      const int cb = ds * 32 + hi5 * 16;
      const bf16x8 k0 = *(const bf16x8*)((const char*)&Ks[cur][0] + lq * 128 + (cb ^ rsw0));
      const bf16x8 k1 = *(const bf16x8*)((const char*)&Ks[cur][0] + (lq + 32) * 128 + (cb ^ rsw0));
      st0 = mfma32(k0, qf[ds], st0);
      st1 = mfma32(k1, qf[ds], st1);
    }
    __builtin_amdgcn_s_setprio(0);
    // ---- online softmax (exp2 domain)
    float ta0 = fmaxf(st0[0], st1[0]), ta1 = fmaxf(st0[1], st1[1]);
    float ta2 = fmaxf(st0[2], st1[2]), ta3 = fmaxf(st0[3], st1[3]);
#pragma unroll
    for (int r = 4; r < 16; r += 4) {
      ta0 = fmaxf(fmaxf(st0[r],     st1[r]),     ta0);
      ta1 = fmaxf(fmaxf(st0[r + 1], st1[r + 1]), ta1);
      ta2 = fmaxf(fmaxf(st0[r + 2], st1[r + 2]), ta2);
      ta3 = fmaxf(fmaxf(st0[r + 3], st1[r + 3]), ta3);
    }
    float tmax = fmaxf(fmaxf(fmaxf(ta0, ta1), ta2), ta3);
    tmax = fmaxf(tmax, __shfl_xor(tmax, 32, 64));
    if (!__all(tmax - m <= 11.5416f)) {          // defer-max, THR = 8*log2e
      const float mn = fmaxf(m, tmax);
      const float sc = exp2f(m - mn);
      l *= sc;
#pragma unroll
      for (int r = 0; r < 16; ++r) { ot0[r] *= sc; ot1[r] *= sc; }
      m = mn;
    }
    float sa0 = 0.f, sa1 = 0.f, sa2 = 0.f, sa3 = 0.f;
#pragma unroll
    for (int r = 0; r < 16; r += 4) {
      float p0 = exp2f(st0[r]     - m); st0[r]     = p0; sa0 += p0;
      float p1 = exp2f(st0[r + 1] - m); st0[r + 1] = p1; sa1 += p1;
      float p2 = exp2f(st0[r + 2] - m); st0[r + 2] = p2; sa2 += p2;
      float p3 = exp2f(st0[r + 3] - m); st0[r + 3] = p3; sa3 += p3;
    }
#pragma unroll
    for (int r = 0; r < 16; r += 4) {
      float p0 = exp2f(st1[r]     - m); st1[r]     = p0; sa0 += p0;
      float p1 = exp2f(st1[r + 1] - m); st1[r + 1] = p1; sa1 += p1;
      float p2 = exp2f(st1[r + 2] - m); st1[r + 2] = p2; sa2 += p2;
      float p3 = exp2f(st1[r + 3] - m); st1[r + 3] = p3; sa3 += p3;
    }
    float ts = (sa0 + sa1) + (sa2 + sa3);
    ts += __shfl_xor(ts, 32, 64);
    l += ts;
    // ---- PV
    __builtin_amdgcn_s_setprio(1);
#pragma unroll
    for (int s4 = 0; s4 < 4; ++s4) {
      const int u = (s4 & 1) * 8;
      float a0, a1, a2, a3, b0, b1, b2, b3;
      if (s4 < 2) {
        a0 = st0[u]; a1 = st0[u + 1]; a2 = st0[u + 2]; a3 = st0[u + 3];
        b0 = st0[u + 4]; b1 = st0[u + 5]; b2 = st0[u + 6]; b3 = st0[u + 7];
      } else {
        a0 = st1[u]; a1 = st1[u + 1]; a2 = st1[u + 2]; a3 = st1[u + 3];
        b0 = st1[u + 4]; b1 = st1[u + 5]; b2 = st1[u + 6]; b3 = st1[u + 7];
      }
      const unsigned L0 = cvtpk(a0, a1), L1 = cvtpk(a2, a3);
      const unsigned H0 = cvtpk(b0, b1), H1 = cvtpk(b2, b3);
      const auto w02 = __builtin_amdgcn_permlane32_swap(L0, H0, false, false);
      const auto w13 = __builtin_amdgcn_permlane32_swap(L1, H1, false, false);
      union BU { unsigned w[4]; bf16x8 v; } pu;
      pu.w[0] = w02[0]; pu.w[1] = w13[0]; pu.w[2] = w02[1]; pu.w[3] = w13[1];
      const int cb = s4 * 32 + hi5 * 16;
      const bf16x8 v0 = *(const bf16x8*)((const char*)&Vs[cur][0] + lq * 128 + (cb ^ rsw0));
      const bf16x8 v1 = *(const bf16x8*)((const char*)&Vs[cur][0] + (lq + 32) * 128 + (cb ^ rsw0));
      ot0 = mfma32(v0, pu.v, ot0);
      ot1 = mfma32(v1, pu.v, ot1);
    }
    __builtin_amdgcn_s_setprio(0);
    if (t + 1 < 16) __syncthreads();   // next tile staged; cur reads drained
    cur ^= 1;
  }
  // ---- epilogue: normalize, transpose via LDS, coalesced store
  const float inv = 1.0f / l;
#pragma unroll
  for (int r = 0; r < 16; ++r) {
    const int d0 = (r & 3) + 8 * (r >> 2) + 4 * hi5;
    osm[wave][lq][d0]      = f2bf(ot0[r] * inv);
    osm[wave][lq][32 + d0] = f2bf(ot1[r] * inv);
  }
  __syncthreads();
  const int col = (lane & 7) * 8;
#pragma unroll
  for (int pass = 0; pass < 4; ++pass) {
    const int row = pass * 8 + (lane >> 3);
    const bf16x8 vv = *(const bf16x8*)&osm[wave][row][col];
    const int qg = blockIdx.y * 128 + wave * 32 + row;
    *(bf16x8*)(att + (size_t)(b * 2048 + qg) * 768 + h * 64 + col) = vv;
  }
}

// ------------------------------------------------------------------- gemm_o
// d_out[8192][1024] = attb[8192][768] x WoT[1024][768]^T + bo (fp32 out)
__global__ __launch_bounds__(256)
void gemm_o(const u16* __restrict__ A, const u16* __restrict__ Bt,
            float* __restrict__ Cp, const float* __restrict__ bias)
{
  __shared__ __align__(16) u16 As[2][64 * 64];
  __shared__ __align__(16) u16 Bs[2][128 * 64];
  const int tid  = threadIdx.x;
  const int lane = tid & 63;
  const int wave = tid >> 6;
  const int bm = blockIdx.x * 64;
  const int bn = blockIdx.y * 128;
  const int wm = (wave >> 1) * 32;
  const int wn = (wave & 1) * 64;
  const int fr = lane & 15;
  const int fk = (lane >> 4) * 8;

  f32x4 acc[2][4] = {};
  const char* gA0 = (const char*)(A  + (size_t)bm * 768);
  const char* gB0 = (const char*)(Bt + (size_t)bn * 768);
  const size_t rowpitch = 1536;

  auto stage = [&](int buf, int k0) {
#pragma unroll
    for (int c = 0; c < 2; ++c) {
      const int off = tid * 16 + c * 4096;
      gload16(gA0 + (size_t)(off >> 7) * rowpitch + 2 * k0 + (off & 127),
              (char*)&As[buf][0] + wave * 1024 + c * 4096);
    }
#pragma unroll
    for (int c = 0; c < 4; ++c) {
      const int off = tid * 16 + c * 4096;
      gload16(gB0 + (size_t)(off >> 7) * rowpitch + 2 * k0 + (off & 127),
              (char*)&Bs[buf][0] + wave * 1024 + c * 4096);
    }
  };

  stage(0, 0);
  __syncthreads();
  int cur = 0;
  for (int t = 0; t < 12; ++t) {
    if (t + 1 < 12) stage(cur ^ 1, (t + 1) * 64);
    bf16x8 af[2][2], bg[4][2];
#pragma unroll
    for (int m = 0; m < 2; ++m)
#pragma unroll
      for (int kk = 0; kk < 2; ++kk)
        af[m][kk] = *(const bf16x8*)&As[cur][(wm + m * 16 + fr) * 64 + kk * 32 + fk];
#pragma unroll
    for (int n = 0; n < 4; ++n)
#pragma unroll
      for (int kk = 0; kk < 2; ++kk)
        bg[n][kk] = *(const bf16x8*)&Bs[cur][(wn + n * 16 + fr) * 64 + kk * 32 + fk];
#pragma unroll
    for (int kk = 0; kk < 2; ++kk)
#pragma unroll
      for (int m = 0; m < 2; ++m)
#pragma unroll
        for (int n = 0; n < 4; ++n)
          acc[m][n] = mfma16(af[m][kk], bg[n][kk], acc[m][n]);
    if (t + 1 < 12) __syncthreads();
    cur ^= 1;
  }

  const int orow0 = bm + wm + 4 * (lane >> 4);
  const int ocol0 = bn + wn + fr;
#pragma unroll
  for (int m = 0; m < 2; ++m)
#pragma unroll
    for (int n = 0; n < 4; ++n)
#pragma unroll
      for (int r = 0; r < 4; ++r) {
        const int row = orow0 + m * 16 + r;
        const int col = ocol0 + n * 16;
        Cp[(size_t)row * 1024 + col] = acc[m][n][r] + bias[col];
      }
}

// ------------------------------------------------------------------ launch
extern "C" void kernel_launch(void* const* d_in, const int* in_sizes, int n_in,
                              void* d_out, int out_size, void* d_ws, size_t ws_size,
                              hipStream_t stream)
{
  const float* x     = (const float*)d_in[0];
  const float* tabx  = (const float*)d_in[1];
  const float* tab_g = (const float*)d_in[2];
  const float* tab_b = (const float*)d_in[3];
  const float* vid_g = (const float*)d_in[4];
  const float* vid_b = (const float*)d_in[5];
  const float* Wq    = (const float*)d_in[6];
  const float* Wk    = (const float*)d_in[7];
  const float* Wv    = (const float*)d_in[8];
  const float* q_g   = (const float*)d_in[9];
  const float* q_b   = (const float*)d_in[10];
  const float* k_g   = (const float*)d_in[11];
  const float* k_b   = (const float*)d_in[12];
  const float* Wo    = (const float*)d_in[13];
  const float* bo    = (const float*)d_in[14];

  char* ws = (char*)d_ws;
  const size_t O_WQT  = 0;
  const size_t O_WKVT = O_WQT  + (size_t)768 * 1024 * 2;   // 1536x1024 (Wk | Wv)
  const size_t O_WOT  = O_WKVT + (size_t)1536 * 1024 * 2;
  const size_t O_XN   = O_WOT  + (size_t)1024 * 768 * 2;
  const size_t O_KVN  = O_XN   + (size_t)8192 * 1024 * 2;
  const size_t O_QPRE = O_KVN  + (size_t)4096 * 1024 * 2;
  const size_t O_KPRE = O_QPRE + (size_t)8192 * 768 * 2;
  const size_t O_QB   = O_KPRE + (size_t)4096 * 768 * 2;
  const size_t O_KB   = O_QB   + (size_t)8192 * 768 * 2;
  const size_t O_VB   = O_KB   + (size_t)4096 * 768 * 2;
  const size_t O_VT   = O_VB   + (size_t)4096 * 768 * 2;
  const size_t O_ATT  = O_QPRE;   // alias: q_pre dead after its LN

  u16*   WqT   = (u16*)(ws + O_WQT);
  u16*   WkvT  = (u16*)(ws + O_WKVT);
  u16*   WoT   = (u16*)(ws + O_WOT);
  u16*   xn    = (u16*)(ws + O_XN);
  u16*   kvn   = (u16*)(ws + O_KVN);
  u16*   q_pre = (u16*)(ws + O_QPRE);
  u16*   k_pre = (u16*)(ws + O_KPRE);
  u16*   qb    = (u16*)(ws + O_QB);
  u16*   kb    = (u16*)(ws + O_KB);
  u16*   vb    = (u16*)(ws + O_VB);
  u16*   vT    = (u16*)(ws + O_VT);
  u16*   attb  = (u16*)(ws + O_ATT);

  prep<<<16128, 256, 0, stream>>>(Wq, Wk, Wv, Wo, WqT, WkvT, WoT,
                                  tabx, tab_g, tab_b, x, vid_g, vid_b, kvn, xn);
  gemm_qkv<<<1536, 256, 0, stream>>>(xn, kvn, WqT, WkvT, q_pre, k_pre, vb);
  ln_tv<<<13056, 256, 0, stream>>>(k_pre, k_g, k_b, kb, q_pre, q_g, q_b, qb, vb, vT);
  attn4<<<dim3(48, 16), 256, 0, stream>>>(qb, kb, vT, attb);
  gemm_o<<<dim3(128, 8), 256, 0, stream>>>(attb, WoT, (float*)d_out, bo);
}